// Round 1
// baseline (795.338 us; speedup 1.0000x reference)
//
#include <hip/hip_runtime.h>
#include <cstdint>

#define BB 8
#define MM 8192
#define SS 128
#define DD 512
#define QQ 32
#define HH 8
#define HDD 64
#define LN_EPS 1e-5f

typedef __bf16 bf16;
typedef __attribute__((ext_vector_type(8))) __bf16 bf16x8;
typedef __attribute__((ext_vector_type(4))) __bf16 bf16x4;
typedef __attribute__((ext_vector_type(4))) float f32x4;

// ---------------- K1: pooled = mean_s context ----------------
__global__ void k_pooled(const float* __restrict__ ctx, float* __restrict__ pooled) {
    int b = blockIdx.x, d = threadIdx.x;  // 512 threads
    const float* p = ctx + (size_t)b * SS * DD + d;
    float s = 0.f;
#pragma unroll 8
    for (int i = 0; i < SS; i++) s += p[(size_t)i * DD];
    pooled[b * DD + d] = s * (1.0f / SS);
}

// ---------------- K2: queries = qp + pooled @ ctx_w^T + ctx_b  (writes output 3) ----
__global__ void k_qproj(const float* __restrict__ pooled, const float* __restrict__ ctx_w,
                        const float* __restrict__ ctx_b, const float* __restrict__ qp,
                        float* __restrict__ q_out) {
    __shared__ float pl[DD];
    int b = blockIdx.x, t = threadIdx.x;  // 512 threads
    pl[t] = pooled[b * DD + t];
    __syncthreads();
    const f32x4* wr = (const f32x4*)(ctx_w + (size_t)t * DD);
    const f32x4* pv = (const f32x4*)pl;
    float acc = 0.f;
#pragma unroll 8
    for (int k = 0; k < DD / 4; k++) {
        f32x4 w = wr[k], p = pv[k];
        acc += w.x * p.x + w.y * p.y + w.z * p.z + w.w * p.w;
    }
    float proj = acc + ctx_b[t];
#pragma unroll 4
    for (int q = 0; q < QQ; q++)
        q_out[((size_t)b * QQ + q) * DD + t] = qp[q * DD + t] + proj;
}

// ---------------- K3: gates = sigmoid(pooled @ gate_w^T + gate_b) (output 2) -------
__global__ void k_gates(const float* __restrict__ pooled, const float* __restrict__ gate_w,
                        const float* __restrict__ gate_b, float* __restrict__ gates_out) {
    int bq = blockIdx.x;  // 256 blocks x 64 threads
    int b = bq >> 5, q = bq & 31, l = threadIdx.x;
    const f32x4* pv = (const f32x4*)(pooled + b * DD);
    const f32x4* wv = (const f32x4*)(gate_w + q * DD);
    float acc = 0.f;
    for (int k = l; k < DD / 4; k += 64) {
        f32x4 p = pv[k], w = wv[k];
        acc += p.x * w.x + p.y * w.y + p.z * w.z + p.w * w.w;
    }
    for (int off = 32; off; off >>= 1) acc += __shfl_xor(acc, off, 64);
    if (l == 0) gates_out[bq] = 1.0f / (1.0f + __expf(-(acc + gate_b[q])));
}

// ---------------- K4: qh = 0.125 * (queries @ wq^T + bq) ----------------
__global__ void k_qh(const float* __restrict__ q_in, const float* __restrict__ in_w,
                     const float* __restrict__ in_b, float* __restrict__ qh) {
    __shared__ float qr[DD];
    int bq = blockIdx.x, t = threadIdx.x;  // 256 threads
    qr[t] = q_in[(size_t)bq * DD + t];
    qr[t + 256] = q_in[(size_t)bq * DD + t + 256];
    __syncthreads();
    const f32x4* qv = (const f32x4*)qr;
#pragma unroll
    for (int jj = 0; jj < 2; jj++) {
        int j = t + jj * 256;
        const f32x4* wv = (const f32x4*)(in_w + (size_t)j * DD);
        float acc = 0.f;
#pragma unroll 8
        for (int k = 0; k < DD / 4; k++) {
            f32x4 w = wv[k], p = qv[k];
            acc += w.x * p.x + w.y * p.y + w.z * p.z + w.w * p.w;
        }
        qh[(size_t)bq * DD + j] = 0.125f * (acc + in_b[j]);
    }
}

// ---------------- K5: fp32 -> bf16 cast (4 elems/thread) ----------------
__global__ void k_cvt(const float* __restrict__ src, bf16* __restrict__ dst, int n4) {
    int i = blockIdx.x * blockDim.x + threadIdx.x;
    if (i >= n4) return;
    f32x4 v = ((const f32x4*)src)[i];
    bf16x4 o;
    o.x = (bf16)v.x; o.y = (bf16)v.y; o.z = (bf16)v.z; o.w = (bf16)v.w;
    ((bf16x4*)dst)[i] = o;
}

// ---------------- K7: KV GEMM: kv = memB @ kvw^T + bias, bf16 out ----------------
// 128x128 tile, BK=64, global_load_lds width 16, mfma_f32_16x16x32_bf16
__global__ __launch_bounds__(256) void k_gemm_kv(const bf16* __restrict__ A,   // 65536 x 512
                                                 const bf16* __restrict__ Bw,  // 1024 x 512
                                                 const float* __restrict__ in_b,
                                                 bf16* __restrict__ Ckv) {     // 65536 x 1024
    __shared__ bf16 sm[2 * 128 * 64];  // 32 KB: A tile then B tile
    bf16* As = sm;
    bf16* Bs = sm + 128 * 64;
    int tid = threadIdx.x;
    int w = tid >> 6, l = tid & 63;
    int bm = blockIdx.x >> 3, bn = blockIdx.x & 7;  // consecutive blocks share A tile
    int wm = w >> 1, wn = w & 1;
    const f32x4 vzero = {0.f, 0.f, 0.f, 0.f};
    f32x4 acc[4][4];
#pragma unroll
    for (int i = 0; i < 4; i++)
#pragma unroll
        for (int j = 0; j < 4; j++) acc[i][j] = vzero;

    int lr = l >> 3;
    int lc = (l & 7) * 8;
    const bf16* Ag = A + (size_t)(bm * 128) * DD;
    const bf16* Bg = Bw + (size_t)(bn * 128) * DD;
    int lq = l & 15, quad = l >> 4;

    for (int k0 = 0; k0 < DD; k0 += 64) {
        __syncthreads();
#pragma unroll
        for (int i = 0; i < 4; i++) {
            int seg = w * 4 + i;
            const bf16* ga = Ag + (size_t)(seg * 8 + lr) * DD + k0 + lc;
            const bf16* gb = Bg + (size_t)(seg * 8 + lr) * DD + k0 + lc;
            __builtin_amdgcn_global_load_lds((const __attribute__((address_space(1))) void*)ga,
                                             (__attribute__((address_space(3))) void*)(As + seg * 512),
                                             16, 0, 0);
            __builtin_amdgcn_global_load_lds((const __attribute__((address_space(1))) void*)gb,
                                             (__attribute__((address_space(3))) void*)(Bs + seg * 512),
                                             16, 0, 0);
        }
        __syncthreads();
#pragma unroll
        for (int ks = 0; ks < 64; ks += 32) {
            bf16x8 af[4], bfr[4];
#pragma unroll
            for (int i = 0; i < 4; i++)
                af[i] = *(const bf16x8*)(As + (wm * 64 + i * 16 + lq) * 64 + ks + quad * 8);
#pragma unroll
            for (int j = 0; j < 4; j++)
                bfr[j] = *(const bf16x8*)(Bs + (wn * 64 + j * 16 + lq) * 64 + ks + quad * 8);
#pragma unroll
            for (int i = 0; i < 4; i++)
#pragma unroll
                for (int j = 0; j < 4; j++)
                    acc[i][j] = __builtin_amdgcn_mfma_f32_16x16x32_bf16(af[i], bfr[j], acc[i][j], 0, 0, 0);
        }
    }
    // epilogue: C layout col=lane&15, row=quad*4+reg
#pragma unroll
    for (int j = 0; j < 4; j++) {
        int c = bn * 128 + wn * 64 + j * 16 + lq;
        float bias = in_b[512 + c];
#pragma unroll
        for (int i = 0; i < 4; i++) {
            int rbase = bm * 128 + wm * 64 + i * 16 + quad * 4;
#pragma unroll
            for (int t = 0; t < 4; t++)
                Ckv[(size_t)(rbase + t) * 1024 + c] = (bf16)(acc[i][j][t] + bias);
        }
    }
}

// ---------------- K8: scores = qh . K, masked -> fp32 scores buffer ----------------
__global__ __launch_bounds__(256) void k_scores(const float* __restrict__ qh,
                                                const bf16* __restrict__ kv,
                                                const int* __restrict__ mask,
                                                float* __restrict__ scores) {
    int blk = blockIdx.x;  // 1024 = B*H*16
    int mt = blk & 15, h = (blk >> 4) & 7, b = blk >> 7;
    int tid = threadIdx.x, w = tid >> 6, l = tid & 63;
    int lq = l & 15, quad = l >> 4;
    int mbase = mt * 512 + w * 128;

    bf16x8 af[2][2];
#pragma unroll
    for (int i = 0; i < 2; i++)
#pragma unroll
        for (int s = 0; s < 2; s++) {
            const float* qp = qh + ((size_t)(b * QQ + i * 16 + lq)) * DD + h * 64 + s * 32 + quad * 8;
            f32x4 q0 = *(const f32x4*)qp;
            f32x4 q1 = *(const f32x4*)(qp + 4);
            bf16x8 v;
            v[0] = (bf16)q0.x; v[1] = (bf16)q0.y; v[2] = (bf16)q0.z; v[3] = (bf16)q0.w;
            v[4] = (bf16)q1.x; v[5] = (bf16)q1.y; v[6] = (bf16)q1.z; v[7] = (bf16)q1.w;
            af[i][s] = v;
        }

    const f32x4 vzero = {0.f, 0.f, 0.f, 0.f};
    f32x4 acc[2][8];
#pragma unroll
    for (int i = 0; i < 2; i++)
#pragma unroll
        for (int n = 0; n < 8; n++) acc[i][n] = vzero;

#pragma unroll
    for (int n = 0; n < 8; n++) {
        int m = mbase + n * 16 + lq;
        const bf16* kp = kv + ((size_t)(b * MM + m)) * 1024 + h * 64 + quad * 8;
        bf16x8 b0 = *(const bf16x8*)kp;
        bf16x8 b1 = *(const bf16x8*)(kp + 32);
#pragma unroll
        for (int i = 0; i < 2; i++) {
            acc[i][n] = __builtin_amdgcn_mfma_f32_16x16x32_bf16(af[i][0], b0, acc[i][n], 0, 0, 0);
            acc[i][n] = __builtin_amdgcn_mfma_f32_16x16x32_bf16(af[i][1], b1, acc[i][n], 0, 0, 0);
        }
    }
#pragma unroll
    for (int n = 0; n < 8; n++) {
        int m = mbase + n * 16 + lq;
        int mv = mask[b * MM + m];
        float ninf = -__builtin_inff();
#pragma unroll
        for (int i = 0; i < 2; i++)
#pragma unroll
            for (int t = 0; t < 4; t++) {
                int q = i * 16 + quad * 4 + t;
                float val = mv ? acc[i][n][t] : ninf;
                scores[((size_t)(b * HH + h) * QQ + q) * MM + m] = val;
            }
    }
}

// ---------------- K9: softmax in-place + attention head-mean (output 1) ------------
__global__ __launch_bounds__(512) void k_softmax(float* __restrict__ scores,
                                                 float* __restrict__ attn_out) {
    __shared__ float sred[8];
    int bq = blockIdx.x;  // 256 blocks
    int b = bq >> 5, q = bq & 31;
    int t = threadIdx.x, wid = t >> 6;
    float am[16];
#pragma unroll
    for (int i = 0; i < 16; i++) am[i] = 0.f;

    for (int h = 0; h < HH; h++) {
        float* row = scores + ((size_t)(b * HH + h) * QQ + q) * MM;
        float x[16];
#pragma unroll
        for (int i = 0; i < 16; i++) x[i] = row[t + i * 512];
        float mx = -__builtin_inff();
#pragma unroll
        for (int i = 0; i < 16; i++) mx = fmaxf(mx, x[i]);
        for (int off = 32; off; off >>= 1) mx = fmaxf(mx, __shfl_xor(mx, off, 64));
        if ((t & 63) == 0) sred[wid] = mx;
        __syncthreads();
        mx = sred[0];
#pragma unroll
        for (int i = 1; i < 8; i++) mx = fmaxf(mx, sred[i]);
        __syncthreads();
        float sum = 0.f;
#pragma unroll
        for (int i = 0; i < 16; i++) {
            x[i] = __expf(x[i] - mx);
            sum += x[i];
        }
        for (int off = 32; off; off >>= 1) sum += __shfl_xor(sum, off, 64);
        if ((t & 63) == 0) sred[wid] = sum;
        __syncthreads();
        float tot = 0.f;
#pragma unroll
        for (int i = 0; i < 8; i++) tot += sred[i];
        float inv = 1.0f / tot;
#pragma unroll
        for (int i = 0; i < 16; i++) {
            float p = x[i] * inv;
            row[t + i * 512] = p;
            am[i] += p;
        }
        __syncthreads();  // protect sred before next h
    }
    float* ao = attn_out + (size_t)bq * MM;
#pragma unroll
    for (int i = 0; i < 16; i++) ao[t + i * 512] = am[i] * (1.0f / HH);
}

// ---------------- K10: ctx = attn @ V ----------------
__global__ __launch_bounds__(256) void k_pv(const float* __restrict__ scores,
                                            const bf16* __restrict__ kv,
                                            float* __restrict__ ctxo) {
    int blk = blockIdx.x;  // 512 = B*H*8
    int qg = blk & 7, h = (blk >> 3) & 7, b = blk >> 6;
    int t = threadIdx.x;
    int ql = t >> 6, d = t & 63;
    int q = qg * 4 + ql;
    const float* P = scores + ((size_t)(b * HH + h) * QQ + q) * MM;
    const bf16* V = kv + (size_t)b * MM * 1024 + 512 + h * 64 + d;
    float acc = 0.f;
    for (int m = 0; m < MM; m += 8) {
        f32x4 p0 = *(const f32x4*)(P + m);
        f32x4 p1 = *(const f32x4*)(P + m + 4);
        float v0 = (float)V[(size_t)(m + 0) * 1024];
        float v1 = (float)V[(size_t)(m + 1) * 1024];
        float v2 = (float)V[(size_t)(m + 2) * 1024];
        float v3 = (float)V[(size_t)(m + 3) * 1024];
        float v4 = (float)V[(size_t)(m + 4) * 1024];
        float v5 = (float)V[(size_t)(m + 5) * 1024];
        float v6 = (float)V[(size_t)(m + 6) * 1024];
        float v7 = (float)V[(size_t)(m + 7) * 1024];
        acc += p0.x * v0 + p0.y * v1 + p0.z * v2 + p0.w * v3;
        acc += p1.x * v4 + p1.y * v5 + p1.z * v6 + p1.w * v7;
    }
    ctxo[((size_t)(b * QQ + q)) * DD + h * 64 + d] = acc;
}

// ---------------- K11: readouts = ctx @ out_w^T + b, gate, LayerNorm (output 0) ----
__global__ __launch_bounds__(256) void k_outln(const float* __restrict__ ctxo,
                                               const float* __restrict__ out_w,
                                               const float* __restrict__ out_b,
                                               const float* __restrict__ gates,
                                               const float* __restrict__ ln_g,
                                               const float* __restrict__ ln_b,
                                               float* __restrict__ out0) {
    __shared__ float cr[DD];
    __shared__ float sred[4], sred2[4];
    int bq = blockIdx.x, t = threadIdx.x;  // 256 threads
    cr[t] = ctxo[(size_t)bq * DD + t];
    cr[t + 256] = ctxo[(size_t)bq * DD + t + 256];
    __syncthreads();
    float g = gates[bq];
    const f32x4* cv = (const f32x4*)cr;
    float r[2];
#pragma unroll
    for (int jj = 0; jj < 2; jj++) {
        int j = t + jj * 256;
        const f32x4* wv = (const f32x4*)(out_w + (size_t)j * DD);
        float acc = 0.f;
#pragma unroll 4
        for (int k = 0; k < DD / 4; k++) {
            f32x4 wq = wv[k], cq = cv[k];
            acc += wq.x * cq.x + wq.y * cq.y + wq.z * cq.z + wq.w * cq.w;
        }
        r[jj] = (acc + out_b[j]) * g;
    }
    float s1 = r[0] + r[1];
    float s2 = r[0] * r[0] + r[1] * r[1];
    for (int off = 32; off; off >>= 1) {
        s1 += __shfl_xor(s1, off, 64);
        s2 += __shfl_xor(s2, off, 64);
    }
    int wid = t >> 6;
    if ((t & 63) == 0) { sred[wid] = s1; sred2[wid] = s2; }
    __syncthreads();
    float S1 = sred[0] + sred[1] + sred[2] + sred[3];
    float S2 = sred2[0] + sred2[1] + sred2[2] + sred2[3];
    float mu = S1 * (1.0f / DD);
    float var = S2 * (1.0f / DD) - mu * mu;
    float rs = rsqrtf(var + LN_EPS);
#pragma unroll
    for (int jj = 0; jj < 2; jj++) {
        int j = t + jj * 256;
        out0[(size_t)bq * DD + j] = (r[jj] - mu) * rs * ln_g[j] + ln_b[j];
    }
}

extern "C" void kernel_launch(void* const* d_in, const int* in_sizes, int n_in,
                              void* d_out, int out_size, void* d_ws, size_t ws_size,
                              hipStream_t stream) {
    const float* memory  = (const float*)d_in[0];
    const float* context = (const float*)d_in[1];
    const int*   mask    = (const int*)d_in[2];
    const float* qp      = (const float*)d_in[3];
    const float* ctx_w   = (const float*)d_in[4];
    const float* ctx_b   = (const float*)d_in[5];
    const float* in_w    = (const float*)d_in[6];
    const float* in_b    = (const float*)d_in[7];
    const float* out_w   = (const float*)d_in[8];
    const float* out_b   = (const float*)d_in[9];
    const float* ln_g    = (const float*)d_in[10];
    const float* ln_b    = (const float*)d_in[11];
    const float* gate_w  = (const float*)d_in[12];
    const float* gate_b  = (const float*)d_in[13];

    float* out       = (float*)d_out;
    float* out_ln    = out;                       // (B,Q,D)   131072
    float* out_attn  = out + 131072;              // (B,Q,M)   2097152
    float* out_gates = out + 131072 + 2097152;    // (B,Q)     256
    float* out_q     = out_gates + 256;           // (B,Q,D)   131072

    char* ws = (char*)d_ws;
    // memB [0, 64MB) is dead after the GEMM; scores aliases it.
    bf16*  memB   = (bf16*)ws;                        // 67108864 B
    float* scores = (float*)ws;                       // 67108864 B (aliases memB)
    bf16*  kvB    = (bf16*)(ws + 67108864);           // 134217728 B
    bf16*  kvwB   = (bf16*)(ws + 201326592);          // 1048576 B
    float* qh     = (float*)(ws + 202375168);         // 524288 B
    float* ctxo   = (float*)(ws + 202899456);         // 524288 B
    float* pooled = (float*)(ws + 203423744);         // 16384 B

    k_pooled<<<BB, 512, 0, stream>>>(context, pooled);
    k_qproj<<<BB, 512, 0, stream>>>(pooled, ctx_w, ctx_b, qp, out_q);
    k_gates<<<BB * QQ, 64, 0, stream>>>(pooled, gate_w, gate_b, out_gates);
    k_qh<<<BB * QQ, 256, 0, stream>>>(out_q, in_w, in_b, qh);
    k_cvt<<<32768, 256, 0, stream>>>(memory, memB, 8388608);
    k_cvt<<<512, 256, 0, stream>>>(in_w + 262144, kvwB, 131072);
    k_gemm_kv<<<4096, 256, 0, stream>>>(memB, kvwB, in_b, kvB);
    k_scores<<<1024, 256, 0, stream>>>(qh, kvB, mask, scores);
    k_softmax<<<BB * QQ, 512, 0, stream>>>(scores, out_attn);
    k_pv<<<512, 256, 0, stream>>>(scores, kvB, ctxo);
    k_outln<<<BB * QQ, 256, 0, stream>>>(ctxo, out_w, out_b, out_gates, ln_g, ln_b, out_ln);
}

// Round 2
// 673.995 us; speedup vs baseline: 1.1800x; 1.1800x over previous
//
#include <hip/hip_runtime.h>
#include <cstdint>

#define BB 8
#define MM 8192
#define SS 128
#define DD 512
#define QQ 32
#define HH 8
#define HDD 64
#define LN_EPS 1e-5f
#define PVCH 16

typedef __bf16 bf16;
typedef __attribute__((ext_vector_type(8))) __bf16 bf16x8;
typedef __attribute__((ext_vector_type(4))) __bf16 bf16x4;
typedef __attribute__((ext_vector_type(4))) float f32x4;

// ---------------- K1: pooled = mean_s context ----------------
__global__ void k_pooled(const float* __restrict__ ctx, float* __restrict__ pooled) {
    int b = blockIdx.x, d = threadIdx.x;  // 512 threads
    const float* p = ctx + (size_t)b * SS * DD + d;
    float s = 0.f;
#pragma unroll 8
    for (int i = 0; i < SS; i++) s += p[(size_t)i * DD];
    pooled[b * DD + d] = s * (1.0f / SS);
}

// ---------------- K2: queries = qp + pooled @ ctx_w^T + ctx_b  (writes output 3) ----
__global__ void k_qproj(const float* __restrict__ pooled, const float* __restrict__ ctx_w,
                        const float* __restrict__ ctx_b, const float* __restrict__ qp,
                        float* __restrict__ q_out) {
    __shared__ float pl[DD];
    int b = blockIdx.x, t = threadIdx.x;  // 512 threads
    pl[t] = pooled[b * DD + t];
    __syncthreads();
    const f32x4* wr = (const f32x4*)(ctx_w + (size_t)t * DD);
    const f32x4* pv = (const f32x4*)pl;
    float acc = 0.f;
#pragma unroll 8
    for (int k = 0; k < DD / 4; k++) {
        f32x4 w = wr[k], p = pv[k];
        acc += w.x * p.x + w.y * p.y + w.z * p.z + w.w * p.w;
    }
    float proj = acc + ctx_b[t];
#pragma unroll 4
    for (int q = 0; q < QQ; q++)
        q_out[((size_t)b * QQ + q) * DD + t] = qp[q * DD + t] + proj;
}

// ---------------- K3: gates = sigmoid(pooled @ gate_w^T + gate_b) (output 2) -------
__global__ void k_gates(const float* __restrict__ pooled, const float* __restrict__ gate_w,
                        const float* __restrict__ gate_b, float* __restrict__ gates_out) {
    int bq = blockIdx.x;  // 256 blocks x 64 threads
    int b = bq >> 5, q = bq & 31, l = threadIdx.x;
    const f32x4* pv = (const f32x4*)(pooled + b * DD);
    const f32x4* wv = (const f32x4*)(gate_w + q * DD);
    float acc = 0.f;
    for (int k = l; k < DD / 4; k += 64) {
        f32x4 p = pv[k], w = wv[k];
        acc += p.x * w.x + p.y * w.y + p.z * w.z + p.w * w.w;
    }
    for (int off = 32; off; off >>= 1) acc += __shfl_xor(acc, off, 64);
    if (l == 0) gates_out[bq] = 1.0f / (1.0f + __expf(-(acc + gate_b[q])));
}

// ---------------- K4: qh = 0.125 * (queries @ wq^T + bq) ----------------
__global__ void k_qh(const float* __restrict__ q_in, const float* __restrict__ in_w,
                     const float* __restrict__ in_b, float* __restrict__ qh) {
    __shared__ float qr[DD];
    int bq = blockIdx.x, t = threadIdx.x;  // 256 threads
    qr[t] = q_in[(size_t)bq * DD + t];
    qr[t + 256] = q_in[(size_t)bq * DD + t + 256];
    __syncthreads();
    const f32x4* qv = (const f32x4*)qr;
#pragma unroll
    for (int jj = 0; jj < 2; jj++) {
        int j = t + jj * 256;
        const f32x4* wv = (const f32x4*)(in_w + (size_t)j * DD);
        float acc = 0.f;
#pragma unroll 8
        for (int k = 0; k < DD / 4; k++) {
            f32x4 w = wv[k], p = qv[k];
            acc += w.x * p.x + w.y * p.y + w.z * p.z + w.w * p.w;
        }
        qh[(size_t)bq * DD + j] = 0.125f * (acc + in_b[j]);
    }
}

// ---------------- K5: fp32 -> bf16 cast (4 elems/thread) ----------------
__global__ void k_cvt(const float* __restrict__ src, bf16* __restrict__ dst, int n4) {
    int i = blockIdx.x * blockDim.x + threadIdx.x;
    if (i >= n4) return;
    f32x4 v = ((const f32x4*)src)[i];
    bf16x4 o;
    o.x = (bf16)v.x; o.y = (bf16)v.y; o.z = (bf16)v.z; o.w = (bf16)v.w;
    ((bf16x4*)dst)[i] = o;
}

// ---------------- K7: KV GEMM: kv = memB @ kvw^T + bias, bf16 out ----------------
// 128x128 tile, BK=64, global_load_lds width 16, mfma_f32_16x16x32_bf16
__global__ __launch_bounds__(256) void k_gemm_kv(const bf16* __restrict__ A,   // 65536 x 512
                                                 const bf16* __restrict__ Bw,  // 1024 x 512
                                                 const float* __restrict__ in_b,
                                                 bf16* __restrict__ Ckv) {     // 65536 x 1024
    __shared__ bf16 sm[2 * 128 * 64];  // 32 KB: A tile then B tile
    bf16* As = sm;
    bf16* Bs = sm + 128 * 64;
    int tid = threadIdx.x;
    int w = tid >> 6, l = tid & 63;
    int bm = blockIdx.x >> 3, bn = blockIdx.x & 7;  // consecutive blocks share A tile
    int wm = w >> 1, wn = w & 1;
    const f32x4 vzero = {0.f, 0.f, 0.f, 0.f};
    f32x4 acc[4][4];
#pragma unroll
    for (int i = 0; i < 4; i++)
#pragma unroll
        for (int j = 0; j < 4; j++) acc[i][j] = vzero;

    int lr = l >> 3;
    int lc = (l & 7) * 8;
    const bf16* Ag = A + (size_t)(bm * 128) * DD;
    const bf16* Bg = Bw + (size_t)(bn * 128) * DD;
    int lq = l & 15, quad = l >> 4;

    for (int k0 = 0; k0 < DD; k0 += 64) {
        __syncthreads();
#pragma unroll
        for (int i = 0; i < 4; i++) {
            int seg = w * 4 + i;
            const bf16* ga = Ag + (size_t)(seg * 8 + lr) * DD + k0 + lc;
            const bf16* gb = Bg + (size_t)(seg * 8 + lr) * DD + k0 + lc;
            __builtin_amdgcn_global_load_lds((const __attribute__((address_space(1))) void*)ga,
                                             (__attribute__((address_space(3))) void*)(As + seg * 512),
                                             16, 0, 0);
            __builtin_amdgcn_global_load_lds((const __attribute__((address_space(1))) void*)gb,
                                             (__attribute__((address_space(3))) void*)(Bs + seg * 512),
                                             16, 0, 0);
        }
        __syncthreads();
#pragma unroll
        for (int ks = 0; ks < 64; ks += 32) {
            bf16x8 af[4], bfr[4];
#pragma unroll
            for (int i = 0; i < 4; i++)
                af[i] = *(const bf16x8*)(As + (wm * 64 + i * 16 + lq) * 64 + ks + quad * 8);
#pragma unroll
            for (int j = 0; j < 4; j++)
                bfr[j] = *(const bf16x8*)(Bs + (wn * 64 + j * 16 + lq) * 64 + ks + quad * 8);
#pragma unroll
            for (int i = 0; i < 4; i++)
#pragma unroll
                for (int j = 0; j < 4; j++)
                    acc[i][j] = __builtin_amdgcn_mfma_f32_16x16x32_bf16(af[i], bfr[j], acc[i][j], 0, 0, 0);
        }
    }
    // epilogue: C layout col=lane&15, row=quad*4+reg
#pragma unroll
    for (int j = 0; j < 4; j++) {
        int c = bn * 128 + wn * 64 + j * 16 + lq;
        float bias = in_b[512 + c];
#pragma unroll
        for (int i = 0; i < 4; i++) {
            int rbase = bm * 128 + wm * 64 + i * 16 + quad * 4;
#pragma unroll
            for (int t = 0; t < 4; t++)
                Ckv[(size_t)(rbase + t) * 1024 + c] = (bf16)(acc[i][j][t] + bias);
        }
    }
}

// ---------------- K8: scores = qh . K, masked -> fp32 scores buffer ----------------
__global__ __launch_bounds__(256) void k_scores(const float* __restrict__ qh,
                                                const bf16* __restrict__ kv,
                                                const int* __restrict__ mask,
                                                float* __restrict__ scores) {
    int blk = blockIdx.x;  // 1024 = B*H*16
    int mt = blk & 15, h = (blk >> 4) & 7, b = blk >> 7;
    int tid = threadIdx.x, w = tid >> 6, l = tid & 63;
    int lq = l & 15, quad = l >> 4;
    int mbase = mt * 512 + w * 128;

    bf16x8 af[2][2];
#pragma unroll
    for (int i = 0; i < 2; i++)
#pragma unroll
        for (int s = 0; s < 2; s++) {
            const float* qp = qh + ((size_t)(b * QQ + i * 16 + lq)) * DD + h * 64 + s * 32 + quad * 8;
            f32x4 q0 = *(const f32x4*)qp;
            f32x4 q1 = *(const f32x4*)(qp + 4);
            bf16x8 v;
            v[0] = (bf16)q0.x; v[1] = (bf16)q0.y; v[2] = (bf16)q0.z; v[3] = (bf16)q0.w;
            v[4] = (bf16)q1.x; v[5] = (bf16)q1.y; v[6] = (bf16)q1.z; v[7] = (bf16)q1.w;
            af[i][s] = v;
        }

    const f32x4 vzero = {0.f, 0.f, 0.f, 0.f};
    f32x4 acc[2][8];
#pragma unroll
    for (int i = 0; i < 2; i++)
#pragma unroll
        for (int n = 0; n < 8; n++) acc[i][n] = vzero;

#pragma unroll
    for (int n = 0; n < 8; n++) {
        int m = mbase + n * 16 + lq;
        const bf16* kp = kv + ((size_t)(b * MM + m)) * 1024 + h * 64 + quad * 8;
        bf16x8 b0 = *(const bf16x8*)kp;
        bf16x8 b1 = *(const bf16x8*)(kp + 32);
#pragma unroll
        for (int i = 0; i < 2; i++) {
            acc[i][n] = __builtin_amdgcn_mfma_f32_16x16x32_bf16(af[i][0], b0, acc[i][n], 0, 0, 0);
            acc[i][n] = __builtin_amdgcn_mfma_f32_16x16x32_bf16(af[i][1], b1, acc[i][n], 0, 0, 0);
        }
    }
#pragma unroll
    for (int n = 0; n < 8; n++) {
        int m = mbase + n * 16 + lq;
        int mv = mask[b * MM + m];
        float ninf = -__builtin_inff();
#pragma unroll
        for (int i = 0; i < 2; i++)
#pragma unroll
            for (int t = 0; t < 4; t++) {
                int q = i * 16 + quad * 4 + t;
                float val = mv ? acc[i][n][t] : ninf;
                scores[((size_t)(b * HH + h) * QQ + q) * MM + m] = val;
            }
    }
}

// ---------------- K9: softmax in-place + attention head-mean (output 1) ------------
// 1024 threads (16 waves) per (b,q) -> 50% occupancy at grid 256
__global__ __launch_bounds__(1024) void k_softmax(float* __restrict__ scores,
                                                  float* __restrict__ attn_out) {
    __shared__ float sred[16];
    int bq = blockIdx.x;  // 256 blocks
    int b = bq >> 5, q = bq & 31;
    int t = threadIdx.x, wid = t >> 6;
    float am[8];
#pragma unroll
    for (int i = 0; i < 8; i++) am[i] = 0.f;

    for (int h = 0; h < HH; h++) {
        float* row = scores + ((size_t)(b * HH + h) * QQ + q) * MM;
        float x[8];
#pragma unroll
        for (int i = 0; i < 8; i++) x[i] = row[t + i * 1024];
        float mx = -__builtin_inff();
#pragma unroll
        for (int i = 0; i < 8; i++) mx = fmaxf(mx, x[i]);
        for (int off = 32; off; off >>= 1) mx = fmaxf(mx, __shfl_xor(mx, off, 64));
        if ((t & 63) == 0) sred[wid] = mx;
        __syncthreads();
#pragma unroll
        for (int i = 0; i < 16; i++) mx = fmaxf(mx, sred[i]);
        __syncthreads();
        float sum = 0.f;
#pragma unroll
        for (int i = 0; i < 8; i++) {
            x[i] = __expf(x[i] - mx);
            sum += x[i];
        }
        for (int off = 32; off; off >>= 1) sum += __shfl_xor(sum, off, 64);
        if ((t & 63) == 0) sred[wid] = sum;
        __syncthreads();
        float tot = 0.f;
#pragma unroll
        for (int i = 0; i < 16; i++) tot += sred[i];
        float inv = 1.0f / tot;
#pragma unroll
        for (int i = 0; i < 8; i++) {
            float p = x[i] * inv;
            row[t + i * 1024] = p;
            am[i] += p;
        }
        __syncthreads();  // protect sred before next h
    }
    float* ao = attn_out + (size_t)bq * MM;
#pragma unroll
    for (int i = 0; i < 8; i++) ao[t + i * 1024] = am[i] * (1.0f / HH);
}

// ---------------- K10: ctx = attn @ V  (split-M partial sums, atomicAdd) ----------
// Block = one (b, h, m-chunk); covers ALL 32 q so V is read exactly once.
// thread: d = t&63, qg = t>>6; 8 q's per thread (q = qg + i*4).
__global__ __launch_bounds__(256) void k_pv(const float* __restrict__ scores,
                                            const bf16* __restrict__ kv,
                                            float* __restrict__ ctxo) {
    int blk = blockIdx.x;  // B*H*PVCH = 1024
    int ck = blk & (PVCH - 1);
    int h = (blk / PVCH) & (HH - 1);
    int b = blk / (PVCH * HH);
    int t = threadIdx.x;
    int d = t & 63, qg = t >> 6;  // qg in 0..3
    int m0 = ck * (MM / PVCH);    // 512 m per chunk
    const bf16* V = kv + (size_t)b * MM * 1024 + (size_t)m0 * 1024 + 512 + h * 64 + d;
    const float* S = scores + ((size_t)(b * HH + h) * QQ) * MM + m0;
    float acc[8];
#pragma unroll
    for (int i = 0; i < 8; i++) acc[i] = 0.f;

    for (int mm = 0; mm < MM / PVCH; mm += 4) {
        float v0 = (float)V[(size_t)(mm + 0) * 1024];
        float v1 = (float)V[(size_t)(mm + 1) * 1024];
        float v2 = (float)V[(size_t)(mm + 2) * 1024];
        float v3 = (float)V[(size_t)(mm + 3) * 1024];
#pragma unroll
        for (int i = 0; i < 8; i++) {
            int q = qg + i * 4;
            f32x4 p = *(const f32x4*)(S + (size_t)q * MM + mm);
            acc[i] += p.x * v0 + p.y * v1 + p.z * v2 + p.w * v3;
        }
    }
#pragma unroll
    for (int i = 0; i < 8; i++) {
        int q = qg + i * 4;
        atomicAdd(&ctxo[((size_t)(b * QQ + q)) * DD + h * 64 + d], acc[i]);
    }
}

// ---------------- K11: readouts = ctx @ out_w^T + b, gate, LayerNorm (output 0) ----
__global__ __launch_bounds__(256) void k_outln(const float* __restrict__ ctxo,
                                               const float* __restrict__ out_w,
                                               const float* __restrict__ out_b,
                                               const float* __restrict__ gates,
                                               const float* __restrict__ ln_g,
                                               const float* __restrict__ ln_b,
                                               float* __restrict__ out0) {
    __shared__ float cr[DD];
    __shared__ float sred[4], sred2[4];
    int bq = blockIdx.x, t = threadIdx.x;  // 256 threads
    cr[t] = ctxo[(size_t)bq * DD + t];
    cr[t + 256] = ctxo[(size_t)bq * DD + t + 256];
    __syncthreads();
    float g = gates[bq];
    const f32x4* cv = (const f32x4*)cr;
    float r[2];
#pragma unroll
    for (int jj = 0; jj < 2; jj++) {
        int j = t + jj * 256;
        const f32x4* wv = (const f32x4*)(out_w + (size_t)j * DD);
        float acc = 0.f;
#pragma unroll 4
        for (int k = 0; k < DD / 4; k++) {
            f32x4 wq = wv[k], cq = cv[k];
            acc += wq.x * cq.x + wq.y * cq.y + wq.z * cq.z + wq.w * cq.w;
        }
        r[jj] = (acc + out_b[j]) * g;
    }
    float s1 = r[0] + r[1];
    float s2 = r[0] * r[0] + r[1] * r[1];
    for (int off = 32; off; off >>= 1) {
        s1 += __shfl_xor(s1, off, 64);
        s2 += __shfl_xor(s2, off, 64);
    }
    int wid = t >> 6;
    if ((t & 63) == 0) { sred[wid] = s1; sred2[wid] = s2; }
    __syncthreads();
    float S1 = sred[0] + sred[1] + sred[2] + sred[3];
    float S2 = sred2[0] + sred2[1] + sred2[2] + sred2[3];
    float mu = S1 * (1.0f / DD);
    float var = S2 * (1.0f / DD) - mu * mu;
    float rs = rsqrtf(var + LN_EPS);
#pragma unroll
    for (int jj = 0; jj < 2; jj++) {
        int j = t + jj * 256;
        out0[(size_t)bq * DD + j] = (r[jj] - mu) * rs * ln_g[j] + ln_b[j];
    }
}

extern "C" void kernel_launch(void* const* d_in, const int* in_sizes, int n_in,
                              void* d_out, int out_size, void* d_ws, size_t ws_size,
                              hipStream_t stream) {
    const float* memory  = (const float*)d_in[0];
    const float* context = (const float*)d_in[1];
    const int*   mask    = (const int*)d_in[2];
    const float* qp      = (const float*)d_in[3];
    const float* ctx_w   = (const float*)d_in[4];
    const float* ctx_b   = (const float*)d_in[5];
    const float* in_w    = (const float*)d_in[6];
    const float* in_b    = (const float*)d_in[7];
    const float* out_w   = (const float*)d_in[8];
    const float* out_b   = (const float*)d_in[9];
    const float* ln_g    = (const float*)d_in[10];
    const float* ln_b    = (const float*)d_in[11];
    const float* gate_w  = (const float*)d_in[12];
    const float* gate_b  = (const float*)d_in[13];

    float* out       = (float*)d_out;
    float* out_ln    = out;                       // (B,Q,D)   131072
    float* out_attn  = out + 131072;              // (B,Q,M)   2097152
    float* out_gates = out + 131072 + 2097152;    // (B,Q)     256
    float* out_q     = out_gates + 256;           // (B,Q,D)   131072

    char* ws = (char*)d_ws;
    // memB [0, 64MB) is dead after the GEMM; scores aliases it.
    bf16*  memB   = (bf16*)ws;                        // 67108864 B
    float* scores = (float*)ws;                       // 67108864 B (aliases memB)
    bf16*  kvB    = (bf16*)(ws + 67108864);           // 134217728 B
    bf16*  kvwB   = (bf16*)(ws + 201326592);          // 1048576 B
    float* qh     = (float*)(ws + 202375168);         // 524288 B
    float* ctxo   = (float*)(ws + 202899456);         // 524288 B
    float* pooled = (float*)(ws + 203423744);         // 16384 B

    k_pooled<<<BB, 512, 0, stream>>>(context, pooled);
    k_qproj<<<BB, 512, 0, stream>>>(pooled, ctx_w, ctx_b, qp, out_q);
    k_gates<<<BB * QQ, 64, 0, stream>>>(pooled, gate_w, gate_b, out_gates);
    k_qh<<<BB * QQ, 256, 0, stream>>>(out_q, in_w, in_b, qh);
    k_cvt<<<32768, 256, 0, stream>>>(memory, memB, 8388608);
    k_cvt<<<512, 256, 0, stream>>>(in_w + 262144, kvwB, 131072);
    hipMemsetAsync(ctxo, 0, (size_t)BB * QQ * DD * sizeof(float), stream);
    k_gemm_kv<<<4096, 256, 0, stream>>>(memB, kvwB, in_b, kvB);
    k_scores<<<1024, 256, 0, stream>>>(qh, kvB, mask, scores);
    k_softmax<<<BB * QQ, 1024, 0, stream>>>(scores, out_attn);
    k_pv<<<BB * HH * PVCH, 256, 0, stream>>>(scores, kvB, ctxo);
    k_outln<<<BB * QQ, 256, 0, stream>>>(ctxo, out_w, out_b, out_gates, ln_g, ln_b, out_ln);
}

// Round 3
// 556.008 us; speedup vs baseline: 1.4304x; 1.2122x over previous
//
#include <hip/hip_runtime.h>
#include <cstdint>

#define BB 8
#define MM 8192
#define SS 128
#define DD 512
#define QQ 32
#define HH 8
#define HDD 64
#define LN_EPS 1e-5f

typedef __bf16 bf16;
typedef __attribute__((ext_vector_type(8))) __bf16 bf16x8;
typedef __attribute__((ext_vector_type(4))) __bf16 bf16x4;
typedef __attribute__((ext_vector_type(4))) float f32x4;

// ---------------- K1: pooled = mean_s context ----------------
__global__ void k_pooled(const float* __restrict__ ctx, float* __restrict__ pooled) {
    int b = blockIdx.x, d = threadIdx.x;  // 512 threads
    const float* p = ctx + (size_t)b * SS * DD + d;
    float s = 0.f;
#pragma unroll 8
    for (int i = 0; i < SS; i++) s += p[(size_t)i * DD];
    pooled[b * DD + d] = s * (1.0f / SS);
}

// ---------------- K2: queries = qp + pooled @ ctx_w^T + ctx_b  (writes output 3) ----
__global__ void k_qproj(const float* __restrict__ pooled, const float* __restrict__ ctx_w,
                        const float* __restrict__ ctx_b, const float* __restrict__ qp,
                        float* __restrict__ q_out) {
    __shared__ float pl[DD];
    int b = blockIdx.x, t = threadIdx.x;  // 512 threads
    pl[t] = pooled[b * DD + t];
    __syncthreads();
    const f32x4* wr = (const f32x4*)(ctx_w + (size_t)t * DD);
    const f32x4* pv = (const f32x4*)pl;
    float acc = 0.f;
#pragma unroll 8
    for (int k = 0; k < DD / 4; k++) {
        f32x4 w = wr[k], p = pv[k];
        acc += w.x * p.x + w.y * p.y + w.z * p.z + w.w * p.w;
    }
    float proj = acc + ctx_b[t];
#pragma unroll 4
    for (int q = 0; q < QQ; q++)
        q_out[((size_t)b * QQ + q) * DD + t] = qp[q * DD + t] + proj;
}

// ---------------- K3: gates = sigmoid(pooled @ gate_w^T + gate_b) (output 2) -------
__global__ void k_gates(const float* __restrict__ pooled, const float* __restrict__ gate_w,
                        const float* __restrict__ gate_b, float* __restrict__ gates_out) {
    int bq = blockIdx.x;  // 256 blocks x 64 threads
    int b = bq >> 5, q = bq & 31, l = threadIdx.x;
    const f32x4* pv = (const f32x4*)(pooled + b * DD);
    const f32x4* wv = (const f32x4*)(gate_w + q * DD);
    float acc = 0.f;
    for (int k = l; k < DD / 4; k += 64) {
        f32x4 p = pv[k], w = wv[k];
        acc += p.x * w.x + p.y * w.y + p.z * w.z + p.w * w.w;
    }
    for (int off = 32; off; off >>= 1) acc += __shfl_xor(acc, off, 64);
    if (l == 0) gates_out[bq] = 1.0f / (1.0f + __expf(-(acc + gate_b[q])));
}

// ---------------- K4: qh = 0.125 * (queries @ wq^T + bq) ----------------
__global__ void k_qh(const float* __restrict__ q_in, const float* __restrict__ in_w,
                     const float* __restrict__ in_b, float* __restrict__ qh) {
    __shared__ float qr[DD];
    int bq = blockIdx.x, t = threadIdx.x;  // 256 threads
    qr[t] = q_in[(size_t)bq * DD + t];
    qr[t + 256] = q_in[(size_t)bq * DD + t + 256];
    __syncthreads();
    const f32x4* qv = (const f32x4*)qr;
#pragma unroll
    for (int jj = 0; jj < 2; jj++) {
        int j = t + jj * 256;
        const f32x4* wv = (const f32x4*)(in_w + (size_t)j * DD);
        float acc = 0.f;
#pragma unroll 8
        for (int k = 0; k < DD / 4; k++) {
            f32x4 w = wv[k], p = qv[k];
            acc += w.x * p.x + w.y * p.y + w.z * p.z + w.w * p.w;
        }
        qh[(size_t)bq * DD + j] = 0.125f * (acc + in_b[j]);
    }
}

// ---------------- K5: fp32 -> bf16 cast (4 elems/thread) ----------------
__global__ void k_cvt(const float* __restrict__ src, bf16* __restrict__ dst, int n4) {
    int i = blockIdx.x * blockDim.x + threadIdx.x;
    if (i >= n4) return;
    f32x4 v = ((const f32x4*)src)[i];
    bf16x4 o;
    o.x = (bf16)v.x; o.y = (bf16)v.y; o.z = (bf16)v.z; o.w = (bf16)v.w;
    ((bf16x4*)dst)[i] = o;
}

// ---------------- K7: KV GEMM: [K|V] = memB @ kvw^T + bias ----------------
// K half -> kvK [B*M][512]; V half -> Vt [(b*512+h*64+d)][8192] (transposed for PV MFMA)
__global__ __launch_bounds__(256) void k_gemm_kv(const bf16* __restrict__ A,   // 65536 x 512
                                                 const bf16* __restrict__ Bw,  // 1024 x 512
                                                 const float* __restrict__ in_b,
                                                 bf16* __restrict__ kvK,
                                                 bf16* __restrict__ Vt) {
    __shared__ bf16 sm[2 * 128 * 64];  // 32 KB: A tile then B tile
    bf16* As = sm;
    bf16* Bs = sm + 128 * 64;
    int tid = threadIdx.x;
    int w = tid >> 6, l = tid & 63;
    int bm = blockIdx.x >> 3, bn = blockIdx.x & 7;  // consecutive blocks share A tile
    int wm = w >> 1, wn = w & 1;
    const f32x4 vzero = {0.f, 0.f, 0.f, 0.f};
    f32x4 acc[4][4];
#pragma unroll
    for (int i = 0; i < 4; i++)
#pragma unroll
        for (int j = 0; j < 4; j++) acc[i][j] = vzero;

    int lr = l >> 3;
    int lc = (l & 7) * 8;
    const bf16* Ag = A + (size_t)(bm * 128) * DD;
    const bf16* Bg = Bw + (size_t)(bn * 128) * DD;
    int lq = l & 15, quad = l >> 4;

    for (int k0 = 0; k0 < DD; k0 += 64) {
        __syncthreads();
#pragma unroll
        for (int i = 0; i < 4; i++) {
            int seg = w * 4 + i;
            const bf16* ga = Ag + (size_t)(seg * 8 + lr) * DD + k0 + lc;
            const bf16* gb = Bg + (size_t)(seg * 8 + lr) * DD + k0 + lc;
            __builtin_amdgcn_global_load_lds((const __attribute__((address_space(1))) void*)ga,
                                             (__attribute__((address_space(3))) void*)(As + seg * 512),
                                             16, 0, 0);
            __builtin_amdgcn_global_load_lds((const __attribute__((address_space(1))) void*)gb,
                                             (__attribute__((address_space(3))) void*)(Bs + seg * 512),
                                             16, 0, 0);
        }
        __syncthreads();
#pragma unroll
        for (int ks = 0; ks < 64; ks += 32) {
            bf16x8 af[4], bfr[4];
#pragma unroll
            for (int i = 0; i < 4; i++)
                af[i] = *(const bf16x8*)(As + (wm * 64 + i * 16 + lq) * 64 + ks + quad * 8);
#pragma unroll
            for (int j = 0; j < 4; j++)
                bfr[j] = *(const bf16x8*)(Bs + (wn * 64 + j * 16 + lq) * 64 + ks + quad * 8);
#pragma unroll
            for (int i = 0; i < 4; i++)
#pragma unroll
                for (int j = 0; j < 4; j++)
                    acc[i][j] = __builtin_amdgcn_mfma_f32_16x16x32_bf16(af[i], bfr[j], acc[i][j], 0, 0, 0);
        }
    }
    // epilogue: C layout col=lane&15, row=quad*4+reg
    if (bn < 4) {
        // K half: columns [0,512)
#pragma unroll
        for (int j = 0; j < 4; j++) {
            int c = bn * 128 + wn * 64 + j * 16 + lq;
            float bias = in_b[512 + c];
#pragma unroll
            for (int i = 0; i < 4; i++) {
                int rbase = bm * 128 + wm * 64 + i * 16 + quad * 4;
#pragma unroll
                for (int t = 0; t < 4; t++)
                    kvK[(size_t)(rbase + t) * 512 + c] = (bf16)(acc[i][j][t] + bias);
            }
        }
    } else {
        // V half: columns [512,1024) -> transposed
#pragma unroll
        for (int j = 0; j < 4; j++) {
            int c = bn * 128 + wn * 64 + j * 16 + lq;  // 512..1023
            float bias = in_b[512 + c];
            int hd = c - 512;  // h*64+d
#pragma unroll
            for (int i = 0; i < 4; i++) {
                int rbase = bm * 128 + wm * 64 + i * 16 + quad * 4;
                int b = rbase >> 13, mb = rbase & 8191;
                bf16x4 pk;
#pragma unroll
                for (int t = 0; t < 4; t++) pk[t] = (bf16)(acc[i][j][t] + bias);
                *(bf16x4*)(Vt + ((size_t)(b * 512 + hd)) * MM + mb) = pk;
            }
        }
    }
}

// ---------------- K8: scores = qh . K, masked -> fp32 scores buffer ----------------
__global__ __launch_bounds__(256) void k_scores(const float* __restrict__ qh,
                                                const bf16* __restrict__ kvK,
                                                const int* __restrict__ mask,
                                                float* __restrict__ scores) {
    int blk = blockIdx.x;  // 1024 = B*H*16
    int mt = blk & 15, h = (blk >> 4) & 7, b = blk >> 7;
    int tid = threadIdx.x, w = tid >> 6, l = tid & 63;
    int lq = l & 15, quad = l >> 4;
    int mbase = mt * 512 + w * 128;

    bf16x8 af[2][2];
#pragma unroll
    for (int i = 0; i < 2; i++)
#pragma unroll
        for (int s = 0; s < 2; s++) {
            const float* qp = qh + ((size_t)(b * QQ + i * 16 + lq)) * DD + h * 64 + s * 32 + quad * 8;
            f32x4 q0 = *(const f32x4*)qp;
            f32x4 q1 = *(const f32x4*)(qp + 4);
            bf16x8 v;
            v[0] = (bf16)q0.x; v[1] = (bf16)q0.y; v[2] = (bf16)q0.z; v[3] = (bf16)q0.w;
            v[4] = (bf16)q1.x; v[5] = (bf16)q1.y; v[6] = (bf16)q1.z; v[7] = (bf16)q1.w;
            af[i][s] = v;
        }

    const f32x4 vzero = {0.f, 0.f, 0.f, 0.f};
    f32x4 acc[2][8];
#pragma unroll
    for (int i = 0; i < 2; i++)
#pragma unroll
        for (int n = 0; n < 8; n++) acc[i][n] = vzero;

#pragma unroll
    for (int n = 0; n < 8; n++) {
        int m = mbase + n * 16 + lq;
        const bf16* kp = kvK + ((size_t)(b * MM + m)) * 512 + h * 64 + quad * 8;
        bf16x8 b0 = *(const bf16x8*)kp;
        bf16x8 b1 = *(const bf16x8*)(kp + 32);
#pragma unroll
        for (int i = 0; i < 2; i++) {
            acc[i][n] = __builtin_amdgcn_mfma_f32_16x16x32_bf16(af[i][0], b0, acc[i][n], 0, 0, 0);
            acc[i][n] = __builtin_amdgcn_mfma_f32_16x16x32_bf16(af[i][1], b1, acc[i][n], 0, 0, 0);
        }
    }
#pragma unroll
    for (int n = 0; n < 8; n++) {
        int m = mbase + n * 16 + lq;
        int mv = mask[b * MM + m];
        float ninf = -__builtin_inff();
#pragma unroll
        for (int i = 0; i < 2; i++)
#pragma unroll
            for (int t = 0; t < 4; t++) {
                int q = i * 16 + quad * 4 + t;
                float val = mv ? acc[i][n][t] : ninf;
                scores[((size_t)(b * HH + h) * QQ + q) * MM + m] = val;
            }
    }
}

// ---------------- K9: softmax: fp32 scores -> bf16 P (in place) + head-mean --------
// Row r fp32 occupies bytes [r*32768, r*32768+32768); bf16 P written into the FRONT
// half of the same row (stride 16384 bf16 elems). Reads of row complete before the
// first __syncthreads; writes happen after -> no hazard.
__global__ __launch_bounds__(1024) void k_softmax(float* __restrict__ scores,
                                                  float* __restrict__ attn_out) {
    __shared__ float sred[16];
    int bq = blockIdx.x;  // 256 blocks
    int b = bq >> 5, q = bq & 31;
    int t = threadIdx.x, wid = t >> 6;
    float am[8];
#pragma unroll
    for (int i = 0; i < 8; i++) am[i] = 0.f;

    for (int h = 0; h < HH; h++) {
        float* row = scores + ((size_t)(b * HH + h) * QQ + q) * MM;
        bf16* prow = (bf16*)row;
        float x[8];
#pragma unroll
        for (int i = 0; i < 8; i++) x[i] = row[t + i * 1024];
        float mx = -__builtin_inff();
#pragma unroll
        for (int i = 0; i < 8; i++) mx = fmaxf(mx, x[i]);
        for (int off = 32; off; off >>= 1) mx = fmaxf(mx, __shfl_xor(mx, off, 64));
        if ((t & 63) == 0) sred[wid] = mx;
        __syncthreads();
#pragma unroll
        for (int i = 0; i < 16; i++) mx = fmaxf(mx, sred[i]);
        __syncthreads();
        float sum = 0.f;
#pragma unroll
        for (int i = 0; i < 8; i++) {
            x[i] = __expf(x[i] - mx);
            sum += x[i];
        }
        for (int off = 32; off; off >>= 1) sum += __shfl_xor(sum, off, 64);
        if ((t & 63) == 0) sred[wid] = sum;
        __syncthreads();
        float tot = 0.f;
#pragma unroll
        for (int i = 0; i < 16; i++) tot += sred[i];
        float inv = 1.0f / tot;
#pragma unroll
        for (int i = 0; i < 8; i++) {
            float p = x[i] * inv;
            prow[t + i * 1024] = (bf16)p;
            am[i] += p;
        }
        __syncthreads();  // protect sred + row storage before next h
    }
    float* ao = attn_out + (size_t)bq * MM;
#pragma unroll
    for (int i = 0; i < 8; i++) ao[t + i * 1024] = am[i] * (1.0f / HH);
}

// ---------------- K10: ctx = P @ V via MFMA ----------------
// Block = (b, h, m-chunk of 1024); wave w covers 256 m. A = P bf16 (rows stride
// 16384), B = Vt. Partial tiles LDS-reduced, written to ctxo_p[chunk].
__global__ __launch_bounds__(256) void k_pv(const bf16* __restrict__ Pb,
                                            const bf16* __restrict__ Vt,
                                            float* __restrict__ ctxo_p) {
    __shared__ float ctile[QQ * HDD];  // 8 KB
    int blk = blockIdx.x;  // 512 = B*H*8
    int ck = blk & 7, h = (blk >> 3) & 7, b = blk >> 6;
    int t = threadIdx.x, w = t >> 6, l = t & 63;
    int lq = l & 15, quad = l >> 4;
    int m0 = ck * 1024 + w * 256;

    const bf16* Prow0 = Pb + ((size_t)((b * HH + h) * QQ + lq)) * 16384 + m0 + quad * 8;
    const bf16* Prow1 = Prow0 + (size_t)16 * 16384;
    const bf16* Vrow = Vt + ((size_t)((b * HH + h) * HDD + lq)) * MM + m0 + quad * 8;

    const f32x4 vzero = {0.f, 0.f, 0.f, 0.f};
    f32x4 acc[2][4];
#pragma unroll
    for (int i = 0; i < 2; i++)
#pragma unroll
        for (int j = 0; j < 4; j++) acc[i][j] = vzero;

#pragma unroll 2
    for (int ks = 0; ks < 256; ks += 32) {
        bf16x8 a0 = *(const bf16x8*)(Prow0 + ks);
        bf16x8 a1 = *(const bf16x8*)(Prow1 + ks);
        bf16x8 bv[4];
#pragma unroll
        for (int j = 0; j < 4; j++) bv[j] = *(const bf16x8*)(Vrow + (size_t)j * 16 * MM + ks);
#pragma unroll
        for (int j = 0; j < 4; j++) {
            acc[0][j] = __builtin_amdgcn_mfma_f32_16x16x32_bf16(a0, bv[j], acc[0][j], 0, 0, 0);
            acc[1][j] = __builtin_amdgcn_mfma_f32_16x16x32_bf16(a1, bv[j], acc[1][j], 0, 0, 0);
        }
    }
    for (int i = t; i < QQ * HDD; i += 256) ctile[i] = 0.f;
    __syncthreads();
#pragma unroll
    for (int i = 0; i < 2; i++)
#pragma unroll
        for (int j = 0; j < 4; j++)
#pragma unroll
            for (int tt = 0; tt < 4; tt++) {
                int q = i * 16 + quad * 4 + tt;
                int d = j * 16 + lq;
                atomicAdd(&ctile[q * HDD + d], acc[i][j][tt]);
            }
    __syncthreads();
    float* dst = ctxo_p + (size_t)ck * (BB * QQ * DD);
    for (int i = t; i < QQ * HDD; i += 256) {
        int q = i >> 6, d = i & 63;
        dst[((size_t)(b * QQ + q)) * DD + h * HDD + d] = ctile[i];
    }
}

// ---------------- K11: readouts = (sum_c ctxo_p) @ out_w^T + b, gate, LN (out 0) ---
__global__ __launch_bounds__(256) void k_outln(const float* __restrict__ ctxo_p,
                                               const float* __restrict__ out_w,
                                               const float* __restrict__ out_b,
                                               const float* __restrict__ gates,
                                               const float* __restrict__ ln_g,
                                               const float* __restrict__ ln_b,
                                               float* __restrict__ out0) {
    __shared__ float cr[DD];
    __shared__ float sred[4], sred2[4];
    int bq = blockIdx.x, t = threadIdx.x;  // 256 threads
    float c0 = 0.f, c1 = 0.f;
#pragma unroll
    for (int c = 0; c < 8; c++) {
        const float* src = ctxo_p + (size_t)c * (BB * QQ * DD) + (size_t)bq * DD;
        c0 += src[t];
        c1 += src[t + 256];
    }
    cr[t] = c0;
    cr[t + 256] = c1;
    __syncthreads();
    float g = gates[bq];
    const f32x4* cv = (const f32x4*)cr;
    float r[2];
#pragma unroll
    for (int jj = 0; jj < 2; jj++) {
        int j = t + jj * 256;
        const f32x4* wv = (const f32x4*)(out_w + (size_t)j * DD);
        float acc = 0.f;
#pragma unroll 4
        for (int k = 0; k < DD / 4; k++) {
            f32x4 wq = wv[k], cq = cv[k];
            acc += wq.x * cq.x + wq.y * cq.y + wq.z * cq.z + wq.w * cq.w;
        }
        r[jj] = (acc + out_b[j]) * g;
    }
    float s1 = r[0] + r[1];
    float s2 = r[0] * r[0] + r[1] * r[1];
    for (int off = 32; off; off >>= 1) {
        s1 += __shfl_xor(s1, off, 64);
        s2 += __shfl_xor(s2, off, 64);
    }
    int wid = t >> 6;
    if ((t & 63) == 0) { sred[wid] = s1; sred2[wid] = s2; }
    __syncthreads();
    float S1 = sred[0] + sred[1] + sred[2] + sred[3];
    float S2 = sred2[0] + sred2[1] + sred2[2] + sred2[3];
    float mu = S1 * (1.0f / DD);
    float var = S2 * (1.0f / DD) - mu * mu;
    float rs = rsqrtf(var + LN_EPS);
#pragma unroll
    for (int jj = 0; jj < 2; jj++) {
        int j = t + jj * 256;
        out0[(size_t)bq * DD + j] = (r[jj] - mu) * rs * ln_g[j] + ln_b[j];
    }
}

extern "C" void kernel_launch(void* const* d_in, const int* in_sizes, int n_in,
                              void* d_out, int out_size, void* d_ws, size_t ws_size,
                              hipStream_t stream) {
    const float* memory  = (const float*)d_in[0];
    const float* context = (const float*)d_in[1];
    const int*   mask    = (const int*)d_in[2];
    const float* qp      = (const float*)d_in[3];
    const float* ctx_w   = (const float*)d_in[4];
    const float* ctx_b   = (const float*)d_in[5];
    const float* in_w    = (const float*)d_in[6];
    const float* in_b    = (const float*)d_in[7];
    const float* out_w   = (const float*)d_in[8];
    const float* out_b   = (const float*)d_in[9];
    const float* ln_g    = (const float*)d_in[10];
    const float* ln_b    = (const float*)d_in[11];
    const float* gate_w  = (const float*)d_in[12];
    const float* gate_b  = (const float*)d_in[13];

    float* out       = (float*)d_out;
    float* out_ln    = out;                       // (B,Q,D)   131072
    float* out_attn  = out + 131072;              // (B,Q,M)   2097152
    float* out_gates = out + 131072 + 2097152;    // (B,Q)     256
    float* out_q     = out_gates + 256;           // (B,Q,D)   131072

    char* ws = (char*)d_ws;
    // memB [0, 64MB) dead after GEMM; scores aliases it; softmax overwrites scores
    // with bf16 P in place (row stride 16384 bf16).
    bf16*  memB   = (bf16*)ws;                        // [0, 67108864)
    float* scores = (float*)ws;                       // alias
    bf16*  Pb     = (bf16*)ws;                        // alias (after softmax)
    bf16*  kvK    = (bf16*)(ws + 67108864);           // 67108864 B
    bf16*  Vt     = (bf16*)(ws + 134217728);          // 67108864 B
    bf16*  kvwB   = (bf16*)(ws + 201326592);          // 1048576 B
    float* qh     = (float*)(ws + 202375168);         // 524288 B
    float* ctxo_p = (float*)(ws + 202899456);         // 4194304 B (8 chunks)
    float* pooled = (float*)(ws + 207093760);         // 16384 B

    k_pooled<<<BB, 512, 0, stream>>>(context, pooled);
    k_qproj<<<BB, 512, 0, stream>>>(pooled, ctx_w, ctx_b, qp, out_q);
    k_gates<<<BB * QQ, 64, 0, stream>>>(pooled, gate_w, gate_b, out_gates);
    k_qh<<<BB * QQ, 256, 0, stream>>>(out_q, in_w, in_b, qh);
    k_cvt<<<32768, 256, 0, stream>>>(memory, memB, 8388608);
    k_cvt<<<512, 256, 0, stream>>>(in_w + 262144, kvwB, 131072);
    k_gemm_kv<<<4096, 256, 0, stream>>>(memB, kvwB, in_b, kvK, Vt);
    k_scores<<<1024, 256, 0, stream>>>(qh, kvK, mask, scores);
    k_softmax<<<BB * QQ, 1024, 0, stream>>>(scores, out_attn);
    k_pv<<<BB * HH * 8, 256, 0, stream>>>(Pb, Vt, ctxo_p);
    k_outln<<<BB * QQ, 256, 0, stream>>>(ctxo_p, out_w, out_b, out_gates, ln_g, ln_b, out_ln);
}

// Round 4
// 507.127 us; speedup vs baseline: 1.5683x; 1.0964x over previous
//
#include <hip/hip_runtime.h>
#include <cstdint>

#define BB 8
#define MM 8192
#define SS 128
#define DD 512
#define QQ 32
#define HH 8
#define HDD 64
#define LN_EPS 1e-5f

typedef __bf16 bf16;
typedef __attribute__((ext_vector_type(8))) __bf16 bf16x8;
typedef __attribute__((ext_vector_type(4))) __bf16 bf16x4;
typedef __attribute__((ext_vector_type(4))) float f32x4;

// ---------------- K1: fused pooled + queries(out3) + gates(out2) ----------------
__global__ __launch_bounds__(512) void k_front(const float* __restrict__ ctx,
                                               const float* __restrict__ ctx_w,
                                               const float* __restrict__ ctx_b,
                                               const float* __restrict__ qp,
                                               const float* __restrict__ gate_w,
                                               const float* __restrict__ gate_b,
                                               float* __restrict__ q_out,
                                               float* __restrict__ gates_out) {
    __shared__ float pl[DD];
    int b = blockIdx.x, t = threadIdx.x;  // 512 threads
    const float* p = ctx + (size_t)b * SS * DD + t;
    float s = 0.f;
#pragma unroll 8
    for (int i = 0; i < SS; i++) s += p[(size_t)i * DD];
    pl[t] = s * (1.0f / SS);
    __syncthreads();
    // queries
    const f32x4* wr = (const f32x4*)(ctx_w + (size_t)t * DD);
    const f32x4* pv = (const f32x4*)pl;
    float acc = 0.f;
#pragma unroll 8
    for (int k = 0; k < DD / 4; k++) {
        f32x4 w = wr[k], pp = pv[k];
        acc += w.x * pp.x + w.y * pp.y + w.z * pp.z + w.w * pp.w;
    }
    float proj = acc + ctx_b[t];
#pragma unroll 4
    for (int q = 0; q < QQ; q++)
        q_out[((size_t)b * QQ + q) * DD + t] = qp[q * DD + t] + proj;
    // gates (threads 0..31)
    if (t < QQ) {
        const f32x4* gw = (const f32x4*)(gate_w + (size_t)t * DD);
        float ga = 0.f;
#pragma unroll 8
        for (int k = 0; k < DD / 4; k++) {
            f32x4 w = gw[k], pp = pv[k];
            ga += w.x * pp.x + w.y * pp.y + w.z * pp.z + w.w * pp.w;
        }
        gates_out[b * QQ + t] = 1.0f / (1.0f + __expf(-(ga + gate_b[t])));
    }
}

// ---------------- K4: qh = 0.125 * (queries @ wq^T + bq) ----------------
__global__ void k_qh(const float* __restrict__ q_in, const float* __restrict__ in_w,
                     const float* __restrict__ in_b, float* __restrict__ qh) {
    __shared__ float qr[DD];
    int bq = blockIdx.x, t = threadIdx.x;  // 256 threads
    qr[t] = q_in[(size_t)bq * DD + t];
    qr[t + 256] = q_in[(size_t)bq * DD + t + 256];
    __syncthreads();
    const f32x4* qv = (const f32x4*)qr;
#pragma unroll
    for (int jj = 0; jj < 2; jj++) {
        int j = t + jj * 256;
        const f32x4* wv = (const f32x4*)(in_w + (size_t)j * DD);
        float acc = 0.f;
#pragma unroll 8
        for (int k = 0; k < DD / 4; k++) {
            f32x4 w = wv[k], p = qv[k];
            acc += w.x * p.x + w.y * p.y + w.z * p.z + w.w * p.w;
        }
        qh[(size_t)bq * DD + j] = 0.125f * (acc + in_b[j]);
    }
}

// ---------------- K5: fp32 -> bf16 cast (4 elems/thread) ----------------
__global__ void k_cvt(const float* __restrict__ src, bf16* __restrict__ dst, int n4) {
    int i = blockIdx.x * blockDim.x + threadIdx.x;
    if (i >= n4) return;
    f32x4 v = ((const f32x4*)src)[i];
    bf16x4 o;
    o.x = (bf16)v.x; o.y = (bf16)v.y; o.z = (bf16)v.z; o.w = (bf16)v.w;
    ((bf16x4*)dst)[i] = o;
}

// ---------------- K7: KV GEMM: [K|V] = memB @ kvw^T + bias ----------------
// 128x128 tile, BK=64, 512 threads (8 waves, 32x64 each).
// XOR-swizzled LDS (chunk c of row r stored at c^(r&7)) -> conflict-free ds_read_b128.
// XCD-aware grid swizzle: the 8 bn-blocks of one bm are == (mod 8) within a 64-window.
// Epilogue through LDS (swizzled) -> coalesced bf16x8 stores; V half transposed to Vt.
__global__ __launch_bounds__(512) void k_gemm_kv(const bf16* __restrict__ A,   // 65536 x 512
                                                 const bf16* __restrict__ Bw,  // 1024 x 512
                                                 const float* __restrict__ in_b,
                                                 bf16* __restrict__ kvK,       // 65536 x 512
                                                 bf16* __restrict__ Vt) {      // (b*512+hd) x 8192
    __shared__ __align__(16) bf16 sm[2 * 128 * 64];  // 32 KB staging; reused as epilogue tile
    bf16* As = sm;
    bf16* Bs = sm + 128 * 64;
    int tid = threadIdx.x;
    int w = tid >> 6, l = tid & 63;
    int bid = blockIdx.x;
    int bn = (bid >> 3) & 7;
    int bm = ((bid >> 6) << 3) | (bid & 7);
    int wm = w >> 1, wn = w & 1;
    const f32x4 vzero = {0.f, 0.f, 0.f, 0.f};
    f32x4 acc[2][4];
#pragma unroll
    for (int i = 0; i < 2; i++)
#pragma unroll
        for (int j = 0; j < 4; j++) acc[i][j] = vzero;

    int lr = l >> 3;           // staging row within seg
    int gc = (l & 7) ^ lr;     // swizzled global 16B-chunk
    const bf16* Ag = A + (size_t)(bm * 128) * DD;
    const bf16* Bg = Bw + (size_t)(bn * 128) * DD;
    int lq = l & 15, quad = l >> 4, lx = lq & 7;

    for (int k0 = 0; k0 < DD; k0 += 64) {
        __syncthreads();
#pragma unroll
        for (int i = 0; i < 2; i++) {
            int seg = w * 2 + i;  // 16 segs x 8 rows
            const bf16* ga = Ag + (size_t)(seg * 8 + lr) * DD + k0 + gc * 8;
            const bf16* gb = Bg + (size_t)(seg * 8 + lr) * DD + k0 + gc * 8;
            __builtin_amdgcn_global_load_lds((const __attribute__((address_space(1))) void*)ga,
                                             (__attribute__((address_space(3))) void*)(As + seg * 512),
                                             16, 0, 0);
            __builtin_amdgcn_global_load_lds((const __attribute__((address_space(1))) void*)gb,
                                             (__attribute__((address_space(3))) void*)(Bs + seg * 512),
                                             16, 0, 0);
        }
        __syncthreads();
#pragma unroll
        for (int kc = 0; kc < 8; kc += 4) {  // kc = 0, 4  (two 32-k halves)
            int ch = (quad + kc) ^ lx;
            bf16x8 af[2], bfr[4];
#pragma unroll
            for (int i = 0; i < 2; i++)
                af[i] = *(const bf16x8*)(As + (wm * 32 + i * 16 + lq) * 64 + ch * 8);
#pragma unroll
            for (int j = 0; j < 4; j++)
                bfr[j] = *(const bf16x8*)(Bs + (wn * 64 + j * 16 + lq) * 64 + ch * 8);
#pragma unroll
            for (int i = 0; i < 2; i++)
#pragma unroll
                for (int j = 0; j < 4; j++)
                    acc[i][j] = __builtin_amdgcn_mfma_f32_16x16x32_bf16(af[i], bfr[j], acc[i][j], 0, 0, 0);
        }
    }

    // ---- epilogue through LDS (tile = 128x128 bf16 = 32 KB, aliases staging) ----
    __syncthreads();
    bf16* tile = sm;
    if (bn < 4) {
        // K half: tile[row][col], col-chunk swizzled by row
#pragma unroll
        for (int j = 0; j < 4; j++) {
            int col = wn * 64 + j * 16 + lq;
            float bias = in_b[512 + bn * 128 + col];
            int cc = col >> 3, cl = col & 7;
#pragma unroll
            for (int i = 0; i < 2; i++) {
                int rbase = wm * 32 + i * 16 + quad * 4;
#pragma unroll
                for (int t = 0; t < 4; t++) {
                    int row = rbase + t;
                    tile[row * 128 + ((cc ^ (row & 15)) << 3) + cl] = (bf16)(acc[i][j][t] + bias);
                }
            }
        }
        __syncthreads();
        for (int idx = tid; idx < 2048; idx += 512) {
            int row = idx >> 4, ch2 = idx & 15;
            bf16x8 v = *(const bf16x8*)(tile + row * 128 + ((ch2 ^ (row & 15)) << 3));
            *(bf16x8*)(kvK + (size_t)(bm * 128 + row) * 512 + bn * 128 + ch2 * 8) = v;
        }
    } else {
        // V half: tileT[col][row], row-chunk swizzled by col
#pragma unroll
        for (int j = 0; j < 4; j++) {
            int col = wn * 64 + j * 16 + lq;
            float bias = in_b[512 + bn * 128 + col];
            int cs = col & 15;
#pragma unroll
            for (int i = 0; i < 2; i++) {
                int rbase = wm * 32 + i * 16 + quad * 4;
#pragma unroll
                for (int t = 0; t < 4; t++) {
                    int row = rbase + t;
                    tile[col * 128 + (((row >> 3) ^ cs) << 3) + (row & 7)] = (bf16)(acc[i][j][t] + bias);
                }
            }
        }
        __syncthreads();
        int b = bm >> 6;
        int m0 = (bm & 63) * 128;
        int hd0 = (bn - 4) * 128;
        for (int idx = tid; idx < 2048; idx += 512) {
            int col = idx >> 4, ch2 = idx & 15;
            bf16x8 v = *(const bf16x8*)(tile + col * 128 + ((ch2 ^ (col & 15)) << 3));
            *(bf16x8*)(Vt + ((size_t)(b * 512 + hd0 + col)) * MM + m0 + ch2 * 8) = v;
        }
    }
}

// ---------------- K8: scores = qh . K, masked -> fp32 scores buffer ----------------
__global__ __launch_bounds__(256) void k_scores(const float* __restrict__ qh,
                                                const bf16* __restrict__ kvK,
                                                const int* __restrict__ mask,
                                                float* __restrict__ scores) {
    int blk = blockIdx.x;  // 1024 = B*H*16
    int mt = blk & 15, h = (blk >> 4) & 7, b = blk >> 7;
    int tid = threadIdx.x, w = tid >> 6, l = tid & 63;
    int lq = l & 15, quad = l >> 4;
    int mbase = mt * 512 + w * 128;

    bf16x8 af[2][2];
#pragma unroll
    for (int i = 0; i < 2; i++)
#pragma unroll
        for (int s = 0; s < 2; s++) {
            const float* qp = qh + ((size_t)(b * QQ + i * 16 + lq)) * DD + h * 64 + s * 32 + quad * 8;
            f32x4 q0 = *(const f32x4*)qp;
            f32x4 q1 = *(const f32x4*)(qp + 4);
            bf16x8 v;
            v[0] = (bf16)q0.x; v[1] = (bf16)q0.y; v[2] = (bf16)q0.z; v[3] = (bf16)q0.w;
            v[4] = (bf16)q1.x; v[5] = (bf16)q1.y; v[6] = (bf16)q1.z; v[7] = (bf16)q1.w;
            af[i][s] = v;
        }

    const f32x4 vzero = {0.f, 0.f, 0.f, 0.f};
    f32x4 acc[2][8];
#pragma unroll
    for (int i = 0; i < 2; i++)
#pragma unroll
        for (int n = 0; n < 8; n++) acc[i][n] = vzero;

#pragma unroll
    for (int n = 0; n < 8; n++) {
        int m = mbase + n * 16 + lq;
        const bf16* kp = kvK + ((size_t)(b * MM + m)) * 512 + h * 64 + quad * 8;
        bf16x8 b0 = *(const bf16x8*)kp;
        bf16x8 b1 = *(const bf16x8*)(kp + 32);
#pragma unroll
        for (int i = 0; i < 2; i++) {
            acc[i][n] = __builtin_amdgcn_mfma_f32_16x16x32_bf16(af[i][0], b0, acc[i][n], 0, 0, 0);
            acc[i][n] = __builtin_amdgcn_mfma_f32_16x16x32_bf16(af[i][1], b1, acc[i][n], 0, 0, 0);
        }
    }
#pragma unroll
    for (int n = 0; n < 8; n++) {
        int m = mbase + n * 16 + lq;
        int mv = mask[b * MM + m];
        float ninf = -__builtin_inff();
#pragma unroll
        for (int i = 0; i < 2; i++)
#pragma unroll
            for (int t = 0; t < 4; t++) {
                int q = i * 16 + quad * 4 + t;
                float val = mv ? acc[i][n][t] : ninf;
                scores[((size_t)(b * HH + h) * QQ + q) * MM + m] = val;
            }
    }
}

// ---------------- K9: softmax: fp32 scores -> bf16 P (in place) + head-mean --------
__global__ __launch_bounds__(1024) void k_softmax(float* __restrict__ scores,
                                                  float* __restrict__ attn_out) {
    __shared__ float sred[16];
    int bq = blockIdx.x;  // 256 blocks
    int b = bq >> 5, q = bq & 31;
    int t = threadIdx.x, wid = t >> 6;
    float am[8];
#pragma unroll
    for (int i = 0; i < 8; i++) am[i] = 0.f;

    for (int h = 0; h < HH; h++) {
        float* row = scores + ((size_t)(b * HH + h) * QQ + q) * MM;
        bf16* prow = (bf16*)row;
        float x[8];
#pragma unroll
        for (int i = 0; i < 8; i++) x[i] = row[t + i * 1024];
        float mx = -__builtin_inff();
#pragma unroll
        for (int i = 0; i < 8; i++) mx = fmaxf(mx, x[i]);
        for (int off = 32; off; off >>= 1) mx = fmaxf(mx, __shfl_xor(mx, off, 64));
        if ((t & 63) == 0) sred[wid] = mx;
        __syncthreads();
#pragma unroll
        for (int i = 0; i < 16; i++) mx = fmaxf(mx, sred[i]);
        __syncthreads();
        float sum = 0.f;
#pragma unroll
        for (int i = 0; i < 8; i++) {
            x[i] = __expf(x[i] - mx);
            sum += x[i];
        }
        for (int off = 32; off; off >>= 1) sum += __shfl_xor(sum, off, 64);
        if ((t & 63) == 0) sred[wid] = sum;
        __syncthreads();
        float tot = 0.f;
#pragma unroll
        for (int i = 0; i < 16; i++) tot += sred[i];
        float inv = 1.0f / tot;
#pragma unroll
        for (int i = 0; i < 8; i++) {
            float p = x[i] * inv;
            prow[t + i * 1024] = (bf16)p;
            am[i] += p;
        }
        __syncthreads();
    }
    float* ao = attn_out + (size_t)bq * MM;
#pragma unroll
    for (int i = 0; i < 8; i++) ao[t + i * 1024] = am[i] * (1.0f / HH);
}

// ---------------- K10: ctx = P @ V via MFMA ----------------
__global__ __launch_bounds__(256) void k_pv(const bf16* __restrict__ Pb,
                                            const bf16* __restrict__ Vt,
                                            float* __restrict__ ctxo_p) {
    __shared__ float ctile[QQ * HDD];  // 8 KB
    int blk = blockIdx.x;  // 512 = B*H*8
    int ck = blk & 7, h = (blk >> 3) & 7, b = blk >> 6;
    int t = threadIdx.x, w = t >> 6, l = t & 63;
    int lq = l & 15, quad = l >> 4;
    int m0 = ck * 1024 + w * 256;

    const bf16* Prow0 = Pb + ((size_t)((b * HH + h) * QQ + lq)) * 16384 + m0 + quad * 8;
    const bf16* Prow1 = Prow0 + (size_t)16 * 16384;
    const bf16* Vrow = Vt + ((size_t)((b * HH + h) * HDD + lq)) * MM + m0 + quad * 8;

    const f32x4 vzero = {0.f, 0.f, 0.f, 0.f};
    f32x4 acc[2][4];
#pragma unroll
    for (int i = 0; i < 2; i++)
#pragma unroll
        for (int j = 0; j < 4; j++) acc[i][j] = vzero;

#pragma unroll 2
    for (int ks = 0; ks < 256; ks += 32) {
        bf16x8 a0 = *(const bf16x8*)(Prow0 + ks);
        bf16x8 a1 = *(const bf16x8*)(Prow1 + ks);
        bf16x8 bv[4];
#pragma unroll
        for (int j = 0; j < 4; j++) bv[j] = *(const bf16x8*)(Vrow + (size_t)j * 16 * MM + ks);
#pragma unroll
        for (int j = 0; j < 4; j++) {
            acc[0][j] = __builtin_amdgcn_mfma_f32_16x16x32_bf16(a0, bv[j], acc[0][j], 0, 0, 0);
            acc[1][j] = __builtin_amdgcn_mfma_f32_16x16x32_bf16(a1, bv[j], acc[1][j], 0, 0, 0);
        }
    }
    for (int i = t; i < QQ * HDD; i += 256) ctile[i] = 0.f;
    __syncthreads();
#pragma unroll
    for (int i = 0; i < 2; i++)
#pragma unroll
        for (int j = 0; j < 4; j++)
#pragma unroll
            for (int tt = 0; tt < 4; tt++) {
                int q = i * 16 + quad * 4 + tt;
                int d = j * 16 + lq;
                atomicAdd(&ctile[q * HDD + d], acc[i][j][tt]);
            }
    __syncthreads();
    float* dst = ctxo_p + (size_t)ck * (BB * QQ * DD);
    for (int i = t; i < QQ * HDD; i += 256) {
        int q = i >> 6, d = i & 63;
        dst[((size_t)(b * QQ + q)) * DD + h * HDD + d] = ctile[i];
    }
}

// ---------------- K11: readouts = (sum_c ctxo_p) @ out_w^T + b, gate, LN (out 0) ---
__global__ __launch_bounds__(256) void k_outln(const float* __restrict__ ctxo_p,
                                               const float* __restrict__ out_w,
                                               const float* __restrict__ out_b,
                                               const float* __restrict__ gates,
                                               const float* __restrict__ ln_g,
                                               const float* __restrict__ ln_b,
                                               float* __restrict__ out0) {
    __shared__ float cr[DD];
    __shared__ float sred[4], sred2[4];
    int bq = blockIdx.x, t = threadIdx.x;  // 256 threads
    float c0 = 0.f, c1 = 0.f;
#pragma unroll
    for (int c = 0; c < 8; c++) {
        const float* src = ctxo_p + (size_t)c * (BB * QQ * DD) + (size_t)bq * DD;
        c0 += src[t];
        c1 += src[t + 256];
    }
    cr[t] = c0;
    cr[t + 256] = c1;
    __syncthreads();
    float g = gates[bq];
    const f32x4* cv = (const f32x4*)cr;
    float r[2];
#pragma unroll
    for (int jj = 0; jj < 2; jj++) {
        int j = t + jj * 256;
        const f32x4* wv = (const f32x4*)(out_w + (size_t)j * DD);
        float acc = 0.f;
#pragma unroll 4
        for (int k = 0; k < DD / 4; k++) {
            f32x4 wq = wv[k], cq = cv[k];
            acc += wq.x * cq.x + wq.y * cq.y + wq.z * cq.z + wq.w * cq.w;
        }
        r[jj] = (acc + out_b[j]) * g;
    }
    float s1 = r[0] + r[1];
    float s2 = r[0] * r[0] + r[1] * r[1];
    for (int off = 32; off; off >>= 1) {
        s1 += __shfl_xor(s1, off, 64);
        s2 += __shfl_xor(s2, off, 64);
    }
    int wid = t >> 6;
    if ((t & 63) == 0) { sred[wid] = s1; sred2[wid] = s2; }
    __syncthreads();
    float S1 = sred[0] + sred[1] + sred[2] + sred[3];
    float S2 = sred2[0] + sred2[1] + sred2[2] + sred2[3];
    float mu = S1 * (1.0f / DD);
    float var = S2 * (1.0f / DD) - mu * mu;
    float rs = rsqrtf(var + LN_EPS);
#pragma unroll
    for (int jj = 0; jj < 2; jj++) {
        int j = t + jj * 256;
        out0[(size_t)bq * DD + j] = (r[jj] - mu) * rs * ln_g[j] + ln_b[j];
    }
}

extern "C" void kernel_launch(void* const* d_in, const int* in_sizes, int n_in,
                              void* d_out, int out_size, void* d_ws, size_t ws_size,
                              hipStream_t stream) {
    const float* memory  = (const float*)d_in[0];
    const float* context = (const float*)d_in[1];
    const int*   mask    = (const int*)d_in[2];
    const float* qp      = (const float*)d_in[3];
    const float* ctx_w   = (const float*)d_in[4];
    const float* ctx_b   = (const float*)d_in[5];
    const float* in_w    = (const float*)d_in[6];
    const float* in_b    = (const float*)d_in[7];
    const float* out_w   = (const float*)d_in[8];
    const float* out_b   = (const float*)d_in[9];
    const float* ln_g    = (const float*)d_in[10];
    const float* ln_b    = (const float*)d_in[11];
    const float* gate_w  = (const float*)d_in[12];
    const float* gate_b  = (const float*)d_in[13];

    float* out       = (float*)d_out;
    float* out_ln    = out;                       // (B,Q,D)   131072
    float* out_attn  = out + 131072;              // (B,Q,M)   2097152
    float* out_gates = out + 131072 + 2097152;    // (B,Q)     256
    float* out_q     = out_gates + 256;           // (B,Q,D)   131072

    char* ws = (char*)d_ws;
    bf16*  memB   = (bf16*)ws;                        // [0, 67108864)
    float* scores = (float*)ws;                       // alias
    bf16*  Pb     = (bf16*)ws;                        // alias (after softmax)
    bf16*  kvK    = (bf16*)(ws + 67108864);           // 67108864 B
    bf16*  Vt     = (bf16*)(ws + 134217728);          // 67108864 B
    bf16*  kvwB   = (bf16*)(ws + 201326592);          // 1048576 B
    float* qh     = (float*)(ws + 202375168);         // 524288 B
    float* ctxo_p = (float*)(ws + 202899456);         // 4194304 B (8 chunks)

    k_front<<<BB, 512, 0, stream>>>(context, ctx_w, ctx_b, qp, gate_w, gate_b, out_q, out_gates);
    k_qh<<<BB * QQ, 256, 0, stream>>>(out_q, in_w, in_b, qh);
    k_cvt<<<32768, 256, 0, stream>>>(memory, memB, 8388608);
    k_cvt<<<512, 256, 0, stream>>>(in_w + 262144, kvwB, 131072);
    k_gemm_kv<<<4096, 512, 0, stream>>>(memB, kvwB, in_b, kvK, Vt);
    k_scores<<<1024, 256, 0, stream>>>(qh, kvK, mask, scores);
    k_softmax<<<BB * QQ, 1024, 0, stream>>>(scores, out_attn);
    k_pv<<<BB * HH * 8, 256, 0, stream>>>(Pb, Vt, ctxo_p);
    k_outln<<<BB * QQ, 256, 0, stream>>>(ctxo_p, out_w, out_b, out_gates, ln_g, ln_b, out_ln);
}

// Round 5
// 484.159 us; speedup vs baseline: 1.6427x; 1.0474x over previous
//
#include <hip/hip_runtime.h>
#include <cstdint>

#define BB 8
#define MM 8192
#define SS 128
#define DD 512
#define QQ 32
#define HH 8
#define HDD 64
#define LN_EPS 1e-5f

typedef __bf16 bf16;
typedef _Float16 f16;
typedef __attribute__((ext_vector_type(8))) __bf16 bf16x8;
typedef __attribute__((ext_vector_type(4))) __bf16 bf16x4;
typedef __attribute__((ext_vector_type(8))) _Float16 f16x8;
typedef __attribute__((ext_vector_type(4))) float f32x4;

#define NEG_INF (-__builtin_inff())

// ---------------- K1: fused pooled + queries(out3) + gates(out2) ----------------
__global__ __launch_bounds__(512) void k_front(const float* __restrict__ ctx,
                                               const float* __restrict__ ctx_w,
                                               const float* __restrict__ ctx_b,
                                               const float* __restrict__ qp,
                                               const float* __restrict__ gate_w,
                                               const float* __restrict__ gate_b,
                                               float* __restrict__ q_out,
                                               float* __restrict__ gates_out) {
    __shared__ float pl[DD];
    int b = blockIdx.x, t = threadIdx.x;  // 512 threads
    const float* p = ctx + (size_t)b * SS * DD + t;
    float s = 0.f;
#pragma unroll 8
    for (int i = 0; i < SS; i++) s += p[(size_t)i * DD];
    pl[t] = s * (1.0f / SS);
    __syncthreads();
    const f32x4* wr = (const f32x4*)(ctx_w + (size_t)t * DD);
    const f32x4* pv = (const f32x4*)pl;
    float acc = 0.f;
#pragma unroll 8
    for (int k = 0; k < DD / 4; k++) {
        f32x4 w = wr[k], pp = pv[k];
        acc += w.x * pp.x + w.y * pp.y + w.z * pp.z + w.w * pp.w;
    }
    float proj = acc + ctx_b[t];
#pragma unroll 4
    for (int q = 0; q < QQ; q++)
        q_out[((size_t)b * QQ + q) * DD + t] = qp[q * DD + t] + proj;
    if (t < QQ) {
        const f32x4* gw = (const f32x4*)(gate_w + (size_t)t * DD);
        float ga = 0.f;
#pragma unroll 8
        for (int k = 0; k < DD / 4; k++) {
            f32x4 w = gw[k], pp = pv[k];
            ga += w.x * pp.x + w.y * pp.y + w.z * pp.z + w.w * pp.w;
        }
        gates_out[b * QQ + t] = 1.0f / (1.0f + __expf(-(ga + gate_b[t])));
    }
}

// ---------------- K4: qh = 0.125 * (queries @ wq^T + bq) ----------------
// 64 blocks = 8 b x 8 j-slices of 64. queries staged in LDS (64 KB), wq read once.
__global__ __launch_bounds__(256) void k_qh(const float* __restrict__ q_in,
                                            const float* __restrict__ in_w,
                                            const float* __restrict__ in_b,
                                            float* __restrict__ qh) {
    __shared__ float qr[QQ * DD];  // 64 KB
    int blk = blockIdx.x;
    int b = blk >> 3, js = blk & 7;
    int t = threadIdx.x;
    const f32x4* src = (const f32x4*)(q_in + (size_t)b * QQ * DD);
    f32x4* dst = (f32x4*)qr;
    for (int i = t; i < QQ * DD / 4; i += 256) dst[i] = src[i];
    __syncthreads();
    int j = js * 64 + (t & 63);
    int qg = t >> 6;  // 0..3 -> q = qg*8 .. qg*8+7
    const f32x4* wv = (const f32x4*)(in_w + (size_t)j * DD);
    float acc[8];
#pragma unroll
    for (int e = 0; e < 8; e++) acc[e] = 0.f;
    for (int k = 0; k < DD / 4; k++) {
        f32x4 w = wv[k];
#pragma unroll
        for (int e = 0; e < 8; e++) {
            f32x4 qq = ((const f32x4*)qr)[(qg * 8 + e) * (DD / 4) + k];
            acc[e] += w.x * qq.x + w.y * qq.y + w.z * qq.z + w.w * qq.w;
        }
    }
    float bias = in_b[j];
#pragma unroll
    for (int e = 0; e < 8; e++) {
        int q = qg * 8 + e;
        qh[((size_t)(b * QQ + q)) * DD + j] = 0.125f * (acc[e] + bias);
    }
}

// ---------------- K5: fp32 -> bf16 cast (4 elems/thread) ----------------
__global__ void k_cvt(const float* __restrict__ src, bf16* __restrict__ dst, int n4) {
    int i = blockIdx.x * blockDim.x + threadIdx.x;
    if (i >= n4) return;
    f32x4 v = ((const f32x4*)src)[i];
    bf16x4 o;
    o.x = (bf16)v.x; o.y = (bf16)v.y; o.z = (bf16)v.z; o.w = (bf16)v.w;
    ((bf16x4*)dst)[i] = o;
}

// ---------------- K7: KV GEMM: [K|V] = memB @ kvw^T + bias ----------------
__global__ __launch_bounds__(512) void k_gemm_kv(const bf16* __restrict__ A,
                                                 const bf16* __restrict__ Bw,
                                                 const float* __restrict__ in_b,
                                                 bf16* __restrict__ kvK,
                                                 bf16* __restrict__ Vt) {
    __shared__ __align__(16) bf16 sm[2 * 128 * 64];
    bf16* As = sm;
    bf16* Bs = sm + 128 * 64;
    int tid = threadIdx.x;
    int w = tid >> 6, l = tid & 63;
    int bid = blockIdx.x;
    int bn = (bid >> 3) & 7;
    int bm = ((bid >> 6) << 3) | (bid & 7);
    int wm = w >> 1, wn = w & 1;
    const f32x4 vzero = {0.f, 0.f, 0.f, 0.f};
    f32x4 acc[2][4];
#pragma unroll
    for (int i = 0; i < 2; i++)
#pragma unroll
        for (int j = 0; j < 4; j++) acc[i][j] = vzero;

    int lr = l >> 3;
    int gc = (l & 7) ^ lr;
    const bf16* Ag = A + (size_t)(bm * 128) * DD;
    const bf16* Bg = Bw + (size_t)(bn * 128) * DD;
    int lq = l & 15, quad = l >> 4, lx = lq & 7;

    for (int k0 = 0; k0 < DD; k0 += 64) {
        __syncthreads();
#pragma unroll
        for (int i = 0; i < 2; i++) {
            int seg = w * 2 + i;
            const bf16* ga = Ag + (size_t)(seg * 8 + lr) * DD + k0 + gc * 8;
            const bf16* gb = Bg + (size_t)(seg * 8 + lr) * DD + k0 + gc * 8;
            __builtin_amdgcn_global_load_lds((const __attribute__((address_space(1))) void*)ga,
                                             (__attribute__((address_space(3))) void*)(As + seg * 512),
                                             16, 0, 0);
            __builtin_amdgcn_global_load_lds((const __attribute__((address_space(1))) void*)gb,
                                             (__attribute__((address_space(3))) void*)(Bs + seg * 512),
                                             16, 0, 0);
        }
        __syncthreads();
#pragma unroll
        for (int kc = 0; kc < 8; kc += 4) {
            int ch = (quad + kc) ^ lx;
            bf16x8 af[2], bfr[4];
#pragma unroll
            for (int i = 0; i < 2; i++)
                af[i] = *(const bf16x8*)(As + (wm * 32 + i * 16 + lq) * 64 + ch * 8);
#pragma unroll
            for (int j = 0; j < 4; j++)
                bfr[j] = *(const bf16x8*)(Bs + (wn * 64 + j * 16 + lq) * 64 + ch * 8);
#pragma unroll
            for (int i = 0; i < 2; i++)
#pragma unroll
                for (int j = 0; j < 4; j++)
                    acc[i][j] = __builtin_amdgcn_mfma_f32_16x16x32_bf16(af[i], bfr[j], acc[i][j], 0, 0, 0);
        }
    }

    __syncthreads();
    bf16* tile = sm;
    if (bn < 4) {
#pragma unroll
        for (int j = 0; j < 4; j++) {
            int col = wn * 64 + j * 16 + lq;
            float bias = in_b[512 + bn * 128 + col];
            int cc = col >> 3, cl = col & 7;
#pragma unroll
            for (int i = 0; i < 2; i++) {
                int rbase = wm * 32 + i * 16 + quad * 4;
#pragma unroll
                for (int t = 0; t < 4; t++) {
                    int row = rbase + t;
                    tile[row * 128 + ((cc ^ (row & 15)) << 3) + cl] = (bf16)(acc[i][j][t] + bias);
                }
            }
        }
        __syncthreads();
        for (int idx = tid; idx < 2048; idx += 512) {
            int row = idx >> 4, ch2 = idx & 15;
            bf16x8 v = *(const bf16x8*)(tile + row * 128 + ((ch2 ^ (row & 15)) << 3));
            *(bf16x8*)(kvK + (size_t)(bm * 128 + row) * 512 + bn * 128 + ch2 * 8) = v;
        }
    } else {
#pragma unroll
        for (int j = 0; j < 4; j++) {
            int col = wn * 64 + j * 16 + lq;
            float bias = in_b[512 + bn * 128 + col];
            int cs = col & 15;
#pragma unroll
            for (int i = 0; i < 2; i++) {
                int rbase = wm * 32 + i * 16 + quad * 4;
#pragma unroll
                for (int t = 0; t < 4; t++) {
                    int row = rbase + t;
                    tile[col * 128 + (((row >> 3) ^ cs) << 3) + (row & 7)] = (bf16)(acc[i][j][t] + bias);
                }
            }
        }
        __syncthreads();
        int b = bm >> 6;
        int m0 = (bm & 63) * 128;
        int hd0 = (bn - 4) * 128;
        for (int idx = tid; idx < 2048; idx += 512) {
            int col = idx >> 4, ch2 = idx & 15;
            bf16x8 v = *(const bf16x8*)(tile + col * 128 + ((ch2 ^ (col & 15)) << 3));
            *(bf16x8*)(Vt + ((size_t)(b * 512 + hd0 + col)) * MM + m0 + ch2 * 8) = v;
        }
    }
}

// ---------------- K8: scores (fp16) + per-chunk softmax stats ----------------
// Block = (b, h, mt-chunk of 512 m). Writes s16 (masked raw scores, fp16) via
// LDS-staged coalesced stores, and per-(chunk,q) max / sumexp(local max) stats.
__global__ __launch_bounds__(256) void k_scores(const float* __restrict__ qh,
                                                const bf16* __restrict__ kvK,
                                                const int* __restrict__ mask,
                                                f16* __restrict__ s16,
                                                float* __restrict__ statsM,
                                                float* __restrict__ statsS) {
    __shared__ __align__(16) f16 tile[QQ * 528];  // 33 KB, row stride 528 (bank-safe)
    __shared__ float smx[QQ][4];
    __shared__ float sse[QQ][4];
    __shared__ float qmax[QQ];
    int blk = blockIdx.x;  // 1024 = B*H*16
    int mt = blk & 15, h = (blk >> 4) & 7, b = blk >> 7;
    int tid = threadIdx.x, w = tid >> 6, l = tid & 63;
    int lq = l & 15, quad = l >> 4;
    int mbase = mt * 512 + w * 128;

    bf16x8 af[2][2];
#pragma unroll
    for (int i = 0; i < 2; i++)
#pragma unroll
        for (int s = 0; s < 2; s++) {
            const float* qp = qh + ((size_t)(b * QQ + i * 16 + lq)) * DD + h * 64 + s * 32 + quad * 8;
            f32x4 q0 = *(const f32x4*)qp;
            f32x4 q1 = *(const f32x4*)(qp + 4);
            bf16x8 v;
            v[0] = (bf16)q0.x; v[1] = (bf16)q0.y; v[2] = (bf16)q0.z; v[3] = (bf16)q0.w;
            v[4] = (bf16)q1.x; v[5] = (bf16)q1.y; v[6] = (bf16)q1.z; v[7] = (bf16)q1.w;
            af[i][s] = v;
        }

    const f32x4 vzero = {0.f, 0.f, 0.f, 0.f};
    f32x4 acc[2][8];
#pragma unroll
    for (int i = 0; i < 2; i++)
#pragma unroll
        for (int n = 0; n < 8; n++) acc[i][n] = vzero;

#pragma unroll
    for (int n = 0; n < 8; n++) {
        int m = mbase + n * 16 + lq;
        const bf16* kp = kvK + ((size_t)(b * MM + m)) * 512 + h * 64 + quad * 8;
        bf16x8 b0 = *(const bf16x8*)kp;
        bf16x8 b1 = *(const bf16x8*)(kp + 32);
#pragma unroll
        for (int i = 0; i < 2; i++) {
            acc[i][n] = __builtin_amdgcn_mfma_f32_16x16x32_bf16(af[i][0], b0, acc[i][n], 0, 0, 0);
            acc[i][n] = __builtin_amdgcn_mfma_f32_16x16x32_bf16(af[i][1], b1, acc[i][n], 0, 0, 0);
        }
    }
    // apply mask into acc
#pragma unroll
    for (int n = 0; n < 8; n++) {
        int mv = mask[b * MM + mbase + n * 16 + lq];
        if (!mv) {
#pragma unroll
            for (int i = 0; i < 2; i++)
#pragma unroll
                for (int t = 0; t < 4; t++) acc[i][n][t] = NEG_INF;
        }
    }
    // per-(i,t) max over n, then over lq lanes
    float mx[2][4];
#pragma unroll
    for (int i = 0; i < 2; i++)
#pragma unroll
        for (int t = 0; t < 4; t++) {
            float m = acc[i][0][t];
#pragma unroll
            for (int n = 1; n < 8; n++) m = fmaxf(m, acc[i][n][t]);
            mx[i][t] = m;
        }
#pragma unroll
    for (int off = 1; off < 16; off <<= 1)
#pragma unroll
        for (int i = 0; i < 2; i++)
#pragma unroll
            for (int t = 0; t < 4; t++) mx[i][t] = fmaxf(mx[i][t], __shfl_xor(mx[i][t], off, 64));
    if (lq == 0) {
#pragma unroll
        for (int i = 0; i < 2; i++)
#pragma unroll
            for (int t = 0; t < 4; t++) smx[i * 16 + quad * 4 + t][w] = mx[i][t];
    }
    __syncthreads();
    if (tid < QQ) qmax[tid] = fmaxf(fmaxf(smx[tid][0], smx[tid][1]), fmaxf(smx[tid][2], smx[tid][3]));
    __syncthreads();
    // sumexp with chunk max
    float se[2][4];
#pragma unroll
    for (int i = 0; i < 2; i++)
#pragma unroll
        for (int t = 0; t < 4; t++) {
            float qm = qmax[i * 16 + quad * 4 + t];
            float s = 0.f;
#pragma unroll
            for (int n = 0; n < 8; n++) s += __expf(acc[i][n][t] - qm);
            se[i][t] = s;
        }
#pragma unroll
    for (int off = 1; off < 16; off <<= 1)
#pragma unroll
        for (int i = 0; i < 2; i++)
#pragma unroll
            for (int t = 0; t < 4; t++) se[i][t] += __shfl_xor(se[i][t], off, 64);
    if (lq == 0) {
#pragma unroll
        for (int i = 0; i < 2; i++)
#pragma unroll
            for (int t = 0; t < 4; t++) sse[i * 16 + quad * 4 + t][w] = se[i][t];
    }
    // stage fp16 scores in LDS (row q, local m; row stride 528 avoids conflicts)
#pragma unroll
    for (int n = 0; n < 8; n++) {
        int mloc = w * 128 + n * 16 + lq;
#pragma unroll
        for (int i = 0; i < 2; i++)
#pragma unroll
            for (int t = 0; t < 4; t++)
                tile[(i * 16 + quad * 4 + t) * 528 + mloc] = (f16)acc[i][n][t];
    }
    __syncthreads();
    if (tid < QQ) {
        statsM[(size_t)blk * QQ + tid] = qmax[tid];
        statsS[(size_t)blk * QQ + tid] = sse[tid][0] + sse[tid][1] + sse[tid][2] + sse[tid][3];
    }
    // coalesced fp16 writeout: 32 rows x 64 chunks of 16 B
    for (int it = tid; it < 2048; it += 256) {
        int q = it >> 6, c = it & 63;
        f16x8 v = *(const f16x8*)(tile + q * 528 + c * 8);
        *(f16x8*)(s16 + ((size_t)((b * HH + h) * QQ + q)) * MM + mt * 512 + c * 8) = v;
    }
}

// ---------------- K9: attention head-mean (output 1) from fp16 scores + stats ------
// Block = (b, q, m-slice of 2048). Fully parallel, no cross-thread reduction.
__global__ __launch_bounds__(256) void k_attn(const f16* __restrict__ s16,
                                              const float* __restrict__ statsM,
                                              const float* __restrict__ statsS,
                                              float* __restrict__ attn_out) {
    __shared__ float cM[128], cS[128], Mh[HH], iLh[HH];
    int blk = blockIdx.x;  // 1024 = B*Q*4
    int ms = blk & 3, q = (blk >> 2) & 31, b = blk >> 7;
    int t = threadIdx.x;
    if (t < 128) {
        int h = t >> 4, c = t & 15;
        size_t sidx = (size_t)(((b * HH + h) * 16 + c)) * QQ + q;
        cM[t] = statsM[sidx];
        cS[t] = statsS[sidx];
    }
    __syncthreads();
    if (t < HH) {
        float M = NEG_INF;
#pragma unroll
        for (int c = 0; c < 16; c++) M = fmaxf(M, cM[t * 16 + c]);
        float L = 0.f;
#pragma unroll
        for (int c = 0; c < 16; c++) L += cS[t * 16 + c] * __expf(cM[t * 16 + c] - M);
        Mh[t] = M;
        iLh[t] = (1.0f / L) * (1.0f / HH);
    }
    __syncthreads();
    int m0 = ms * 2048 + t * 8;
    float am[8];
#pragma unroll
    for (int e = 0; e < 8; e++) am[e] = 0.f;
#pragma unroll
    for (int h = 0; h < HH; h++) {
        f16x8 v = *(const f16x8*)(s16 + ((size_t)((b * HH + h) * QQ + q)) * MM + m0);
        float M = Mh[h], iL = iLh[h];
#pragma unroll
        for (int e = 0; e < 8; e++) am[e] += __expf((float)v[e] - M) * iL;
    }
    float* ao = attn_out + (size_t)(b * QQ + q) * MM + m0;
    f32x4 o0 = {am[0], am[1], am[2], am[3]};
    f32x4 o1 = {am[4], am[5], am[6], am[7]};
    *(f32x4*)ao = o0;
    *(f32x4*)(ao + 4) = o1;
}

// ---------------- K10: ctx = P @ V via MFMA, P computed on the fly ----------------
__global__ __launch_bounds__(256) void k_pv(const f16* __restrict__ s16,
                                            const float* __restrict__ statsM,
                                            const float* __restrict__ statsS,
                                            const bf16* __restrict__ Vt,
                                            float* __restrict__ ctxo_p) {
    __shared__ float ctile[QQ * HDD];  // 8 KB
    __shared__ float Mq[QQ], iLq[QQ];
    int blk = blockIdx.x;  // 512 = B*H*8
    int ck = blk & 7, h = (blk >> 3) & 7, b = blk >> 6;
    int t = threadIdx.x, w = t >> 6, l = t & 63;
    int lq = l & 15, quad = l >> 4;
    if (t < QQ) {
        const float* pM = statsM + (size_t)((b * HH + h) * 16) * QQ + t;
        const float* pS = statsS + (size_t)((b * HH + h) * 16) * QQ + t;
        float M = NEG_INF;
#pragma unroll
        for (int c = 0; c < 16; c++) M = fmaxf(M, pM[c * QQ]);
        float L = 0.f;
#pragma unroll
        for (int c = 0; c < 16; c++) L += pS[c * QQ] * __expf(pM[c * QQ] - M);
        Mq[t] = M;
        iLq[t] = 1.0f / L;
    }
    __syncthreads();
    int m0 = ck * 1024 + w * 256;

    const f16* P0 = s16 + ((size_t)((b * HH + h) * QQ + lq)) * MM + m0 + quad * 8;
    const f16* P1 = P0 + (size_t)16 * MM;
    const bf16* Vrow = Vt + ((size_t)((b * HH + h) * HDD + lq)) * MM + m0 + quad * 8;
    float M0 = Mq[lq], iL0 = iLq[lq];
    float M1 = Mq[16 + lq], iL1 = iLq[16 + lq];

    const f32x4 vzero = {0.f, 0.f, 0.f, 0.f};
    f32x4 acc[2][4];
#pragma unroll
    for (int i = 0; i < 2; i++)
#pragma unroll
        for (int j = 0; j < 4; j++) acc[i][j] = vzero;

#pragma unroll 2
    for (int ks = 0; ks < 256; ks += 32) {
        f16x8 r0 = *(const f16x8*)(P0 + ks);
        f16x8 r1 = *(const f16x8*)(P1 + ks);
        bf16x8 a0, a1;
#pragma unroll
        for (int e = 0; e < 8; e++) a0[e] = (bf16)(__expf((float)r0[e] - M0) * iL0);
#pragma unroll
        for (int e = 0; e < 8; e++) a1[e] = (bf16)(__expf((float)r1[e] - M1) * iL1);
        bf16x8 bv[4];
#pragma unroll
        for (int j = 0; j < 4; j++) bv[j] = *(const bf16x8*)(Vrow + (size_t)j * 16 * MM + ks);
#pragma unroll
        for (int j = 0; j < 4; j++) {
            acc[0][j] = __builtin_amdgcn_mfma_f32_16x16x32_bf16(a0, bv[j], acc[0][j], 0, 0, 0);
            acc[1][j] = __builtin_amdgcn_mfma_f32_16x16x32_bf16(a1, bv[j], acc[1][j], 0, 0, 0);
        }
    }
    for (int i = t; i < QQ * HDD; i += 256) ctile[i] = 0.f;
    __syncthreads();
#pragma unroll
    for (int i = 0; i < 2; i++)
#pragma unroll
        for (int j = 0; j < 4; j++)
#pragma unroll
            for (int tt = 0; tt < 4; tt++) {
                int q = i * 16 + quad * 4 + tt;
                int d = j * 16 + lq;
                atomicAdd(&ctile[q * HDD + d], acc[i][j][tt]);
            }
    __syncthreads();
    float* dst = ctxo_p + (size_t)ck * (BB * QQ * DD);
    for (int i = t; i < QQ * HDD; i += 256) {
        int q = i >> 6, d = i & 63;
        dst[((size_t)(b * QQ + q)) * DD + h * HDD + d] = ctile[i];
    }
}

// ---------------- K11: readouts = (sum_c ctxo_p) @ out_w^T + b, gate, LN (out 0) ---
__global__ __launch_bounds__(256) void k_outln(const float* __restrict__ ctxo_p,
                                               const float* __restrict__ out_w,
                                               const float* __restrict__ out_b,
                                               const float* __restrict__ gates,
                                               const float* __restrict__ ln_g,
                                               const float* __restrict__ ln_b,
                                               float* __restrict__ out0) {
    __shared__ float cr[DD];
    __shared__ float sred[4], sred2[4];
    int bq = blockIdx.x, t = threadIdx.x;  // 256 threads
    float c0 = 0.f, c1 = 0.f;
#pragma unroll
    for (int c = 0; c < 8; c++) {
        const float* src = ctxo_p + (size_t)c * (BB * QQ * DD) + (size_t)bq * DD;
        c0 += src[t];
        c1 += src[t + 256];
    }
    cr[t] = c0;
    cr[t + 256] = c1;
    __syncthreads();
    float g = gates[bq];
    const f32x4* cv = (const f32x4*)cr;
    float r[2];
#pragma unroll
    for (int jj = 0; jj < 2; jj++) {
        int j = t + jj * 256;
        const f32x4* wv = (const f32x4*)(out_w + (size_t)j * DD);
        float acc = 0.f;
#pragma unroll 4
        for (int k = 0; k < DD / 4; k++) {
            f32x4 wq = wv[k], cq = cv[k];
            acc += wq.x * cq.x + wq.y * cq.y + wq.z * cq.z + wq.w * cq.w;
        }
        r[jj] = (acc + out_b[j]) * g;
    }
    float s1 = r[0] + r[1];
    float s2 = r[0] * r[0] + r[1] * r[1];
    for (int off = 32; off; off >>= 1) {
        s1 += __shfl_xor(s1, off, 64);
        s2 += __shfl_xor(s2, off, 64);
    }
    int wid = t >> 6;
    if ((t & 63) == 0) { sred[wid] = s1; sred2[wid] = s2; }
    __syncthreads();
    float S1 = sred[0] + sred[1] + sred[2] + sred[3];
    float S2 = sred2[0] + sred2[1] + sred2[2] + sred2[3];
    float mu = S1 * (1.0f / DD);
    float var = S2 * (1.0f / DD) - mu * mu;
    float rs = rsqrtf(var + LN_EPS);
#pragma unroll
    for (int jj = 0; jj < 2; jj++) {
        int j = t + jj * 256;
        out0[(size_t)bq * DD + j] = (r[jj] - mu) * rs * ln_g[j] + ln_b[j];
    }
}

extern "C" void kernel_launch(void* const* d_in, const int* in_sizes, int n_in,
                              void* d_out, int out_size, void* d_ws, size_t ws_size,
                              hipStream_t stream) {
    const float* memory  = (const float*)d_in[0];
    const float* context = (const float*)d_in[1];
    const int*   mask    = (const int*)d_in[2];
    const float* qp      = (const float*)d_in[3];
    const float* ctx_w   = (const float*)d_in[4];
    const float* ctx_b   = (const float*)d_in[5];
    const float* in_w    = (const float*)d_in[6];
    const float* in_b    = (const float*)d_in[7];
    const float* out_w   = (const float*)d_in[8];
    const float* out_b   = (const float*)d_in[9];
    const float* ln_g    = (const float*)d_in[10];
    const float* ln_b    = (const float*)d_in[11];
    const float* gate_w  = (const float*)d_in[12];
    const float* gate_b  = (const float*)d_in[13];

    float* out       = (float*)d_out;
    float* out_ln    = out;                       // (B,Q,D)   131072
    float* out_attn  = out + 131072;              // (B,Q,M)   2097152
    float* out_gates = out + 131072 + 2097152;    // (B,Q)     256
    float* out_q     = out_gates + 256;           // (B,Q,D)   131072

    char* ws = (char*)d_ws;
    bf16*  memB   = (bf16*)ws;                        // [0, 64MB); dead after gemm
    f16*   s16    = (f16*)ws;                         // alias: 33.5 MB fp16 scores
    bf16*  kvK    = (bf16*)(ws + 67108864);           // 64 MB
    bf16*  Vt     = (bf16*)(ws + 134217728);          // 64 MB
    bf16*  kvwB   = (bf16*)(ws + 201326592);          // 256 KB
    float* statsM = (float*)(ws + 201588736);         // 128 KB
    float* statsS = (float*)(ws + 201719808);         // 128 KB
    float* qh     = (float*)(ws + 202375168);         // 512 KB
    float* ctxo_p = (float*)(ws + 202899456);         // 4 MB (8 chunks)

    k_front<<<BB, 512, 0, stream>>>(context, ctx_w, ctx_b, qp, gate_w, gate_b, out_q, out_gates);
    k_qh<<<64, 256, 0, stream>>>(out_q, in_w, in_b, qh);
    k_cvt<<<32768, 256, 0, stream>>>(memory, memB, 8388608);
    k_cvt<<<512, 256, 0, stream>>>(in_w + 262144, kvwB, 131072);
    k_gemm_kv<<<4096, 512, 0, stream>>>(memB, kvwB, in_b, kvK, Vt);
    k_scores<<<1024, 256, 0, stream>>>(qh, kvK, mask, s16, statsM, statsS);
    k_attn<<<1024, 256, 0, stream>>>(s16, statsM, statsS, out_attn);
    k_pv<<<512, 256, 0, stream>>>(s16, statsM, statsS, Vt, ctxo_p);
    k_outln<<<BB * QQ, 256, 0, stream>>>(ctxo_p, out_w, out_b, out_gates, ln_g, ln_b, out_ln);
}

// Round 6
// 480.454 us; speedup vs baseline: 1.6554x; 1.0077x over previous
//
#include <hip/hip_runtime.h>
#include <cstdint>

#define BB 8
#define MM 8192
#define SS 128
#define DD 512
#define QQ 32
#define HH 8
#define HDD 64
#define LN_EPS 1e-5f

typedef __bf16 bf16;
typedef _Float16 f16;
typedef __attribute__((ext_vector_type(8))) __bf16 bf16x8;
typedef __attribute__((ext_vector_type(4))) __bf16 bf16x4;
typedef __attribute__((ext_vector_type(8))) _Float16 f16x8;
typedef __attribute__((ext_vector_type(4))) float f32x4;

#define NEG_INF (-__builtin_inff())

// ---------------- K1: fused pooled + queries(out3) + gates(out2) ----------------
// 64 blocks = 8 b x 8 column-slices; pooled recomputed per block (L2-cheap).
__global__ __launch_bounds__(512) void k_front(const float* __restrict__ ctx,
                                               const float* __restrict__ ctx_w,
                                               const float* __restrict__ ctx_b,
                                               const float* __restrict__ qp,
                                               const float* __restrict__ gate_w,
                                               const float* __restrict__ gate_b,
                                               float* __restrict__ q_out,
                                               float* __restrict__ gates_out) {
    __shared__ float pl[DD];
    __shared__ float scratch[512];
    __shared__ float proj[64];
    int blk = blockIdx.x;
    int b = blk >> 3, js = blk & 7;
    int t = threadIdx.x;
    // pooled (full 512-d, one thread per d)
    const float* p = ctx + (size_t)b * SS * DD + t;
    float s = 0.f;
#pragma unroll 8
    for (int i = 0; i < SS; i++) s += p[(size_t)i * DD];
    pl[t] = s * (1.0f / SS);
    __syncthreads();
    // projection rows js*64..+63; 8 threads per row, 64-k slices each
    int r = js * 64 + (t & 63), ks = t >> 6;
    {
        const f32x4* wr = (const f32x4*)(ctx_w + (size_t)r * DD + ks * 64);
        const f32x4* pv = (const f32x4*)(pl + ks * 64);
        float a = 0.f;
#pragma unroll
        for (int k = 0; k < 16; k++) {
            f32x4 w = wr[k], pp = pv[k];
            a += w.x * pp.x + w.y * pp.y + w.z * pp.z + w.w * pp.w;
        }
        scratch[t] = a;
    }
    __syncthreads();
    if (t < 64) {
        float sum = ctx_b[js * 64 + t];
#pragma unroll
        for (int s8 = 0; s8 < 8; s8++) sum += scratch[t + 64 * s8];
        proj[t] = sum;
    }
    __syncthreads();
    // write queries: thread t handles col = js*64+(t&63), q = (t>>6)*4 + qq
    int col = js * 64 + (t & 63);
    float pr = proj[t & 63];
#pragma unroll
    for (int qq = 0; qq < 4; qq++) {
        int q = (t >> 6) * 4 + qq;
        q_out[((size_t)(b * QQ + q)) * DD + col] = qp[q * DD + col] + pr;
    }
    // gates (only js==0 block, threads 0..31)
    if (js == 0 && t < QQ) {
        const f32x4* gw = (const f32x4*)(gate_w + (size_t)t * DD);
        const f32x4* pv = (const f32x4*)pl;
        float ga = 0.f;
#pragma unroll 8
        for (int k = 0; k < DD / 4; k++) {
            f32x4 w = gw[k], pp = pv[k];
            ga += w.x * pp.x + w.y * pp.y + w.z * pp.z + w.w * pp.w;
        }
        gates_out[b * QQ + t] = 1.0f / (1.0f + __expf(-(ga + gate_b[t])));
    }
}

// ---------------- K4: qh = 0.125 * (queries @ wq^T + bq) ----------------
__global__ __launch_bounds__(256) void k_qh(const float* __restrict__ q_in,
                                            const float* __restrict__ in_w,
                                            const float* __restrict__ in_b,
                                            float* __restrict__ qh) {
    __shared__ float qr[QQ * DD];  // 64 KB
    int blk = blockIdx.x;
    int b = blk >> 3, js = blk & 7;
    int t = threadIdx.x;
    const f32x4* src = (const f32x4*)(q_in + (size_t)b * QQ * DD);
    f32x4* dst = (f32x4*)qr;
    for (int i = t; i < QQ * DD / 4; i += 256) dst[i] = src[i];
    __syncthreads();
    int j = js * 64 + (t & 63);
    int qg = t >> 6;
    const f32x4* wv = (const f32x4*)(in_w + (size_t)j * DD);
    float acc[8];
#pragma unroll
    for (int e = 0; e < 8; e++) acc[e] = 0.f;
    for (int k = 0; k < DD / 4; k++) {
        f32x4 w = wv[k];
#pragma unroll
        for (int e = 0; e < 8; e++) {
            f32x4 qq = ((const f32x4*)qr)[(qg * 8 + e) * (DD / 4) + k];
            acc[e] += w.x * qq.x + w.y * qq.y + w.z * qq.z + w.w * qq.w;
        }
    }
    float bias = in_b[j];
#pragma unroll
    for (int e = 0; e < 8; e++) {
        int q = qg * 8 + e;
        qh[((size_t)(b * QQ + q)) * DD + j] = 0.125f * (acc[e] + bias);
    }
}

// ---------------- K5: fp32 -> bf16 cast (4 elems/thread) ----------------
__global__ void k_cvt(const float* __restrict__ src, bf16* __restrict__ dst, int n4) {
    int i = blockIdx.x * blockDim.x + threadIdx.x;
    if (i >= n4) return;
    f32x4 v = ((const f32x4*)src)[i];
    bf16x4 o;
    o.x = (bf16)v.x; o.y = (bf16)v.y; o.z = (bf16)v.z; o.w = (bf16)v.w;
    ((bf16x4*)dst)[i] = o;
}

// ---------------- K7: KV GEMM: [K|V] = memB @ kvw^T + bias ----------------
// 128x128 tile, BK=64, 256 threads (4 waves, 64x64 each) -> 16 MFMA : 8 ds_read
// per wave-BK32 (LDS-pressure optimal). XOR-swizzled LDS; XCD-aware grid;
// swizzled LDS epilogue (V half transposed to Vt).
__global__ __launch_bounds__(256) void k_gemm_kv(const bf16* __restrict__ A,
                                                 const bf16* __restrict__ Bw,
                                                 const float* __restrict__ in_b,
                                                 bf16* __restrict__ kvK,
                                                 bf16* __restrict__ Vt) {
    __shared__ __align__(16) bf16 sm[2 * 128 * 64];  // 32 KB
    bf16* As = sm;
    bf16* Bs = sm + 128 * 64;
    int tid = threadIdx.x;
    int w = tid >> 6, l = tid & 63;
    int bid = blockIdx.x;
    int bn = (bid >> 3) & 7;
    int bm = ((bid >> 6) << 3) | (bid & 7);
    int wm = w >> 1, wn = w & 1;
    const f32x4 vzero = {0.f, 0.f, 0.f, 0.f};
    f32x4 acc[4][4];
#pragma unroll
    for (int i = 0; i < 4; i++)
#pragma unroll
        for (int j = 0; j < 4; j++) acc[i][j] = vzero;

    int lr = l >> 3;
    int gc = (l & 7) ^ lr;
    const bf16* Ag = A + (size_t)(bm * 128) * DD;
    const bf16* Bg = Bw + (size_t)(bn * 128) * DD;
    int lq = l & 15, quad = l >> 4, lx = lq & 7;

    for (int k0 = 0; k0 < DD; k0 += 64) {
        __syncthreads();
#pragma unroll
        for (int i = 0; i < 4; i++) {
            int seg = w * 4 + i;  // 16 segs x (8 rows x 64 k)
            const bf16* ga = Ag + (size_t)(seg * 8 + lr) * DD + k0 + gc * 8;
            const bf16* gb = Bg + (size_t)(seg * 8 + lr) * DD + k0 + gc * 8;
            __builtin_amdgcn_global_load_lds((const __attribute__((address_space(1))) void*)ga,
                                             (__attribute__((address_space(3))) void*)(As + seg * 512),
                                             16, 0, 0);
            __builtin_amdgcn_global_load_lds((const __attribute__((address_space(1))) void*)gb,
                                             (__attribute__((address_space(3))) void*)(Bs + seg * 512),
                                             16, 0, 0);
        }
        __syncthreads();
#pragma unroll
        for (int kc = 0; kc < 8; kc += 4) {
            int ch = (quad + kc) ^ lx;
            bf16x8 af[4], bfr[4];
#pragma unroll
            for (int i = 0; i < 4; i++)
                af[i] = *(const bf16x8*)(As + (wm * 64 + i * 16 + lq) * 64 + ch * 8);
#pragma unroll
            for (int j = 0; j < 4; j++)
                bfr[j] = *(const bf16x8*)(Bs + (wn * 64 + j * 16 + lq) * 64 + ch * 8);
#pragma unroll
            for (int i = 0; i < 4; i++)
#pragma unroll
                for (int j = 0; j < 4; j++)
                    acc[i][j] = __builtin_amdgcn_mfma_f32_16x16x32_bf16(af[i], bfr[j], acc[i][j], 0, 0, 0);
        }
    }

    // ---- epilogue through LDS (128x128 bf16 = 32 KB, aliases staging) ----
    __syncthreads();
    bf16* tile = sm;
    if (bn < 4) {
        // K half: tile[row][col], col-chunk swizzled by row
#pragma unroll
        for (int j = 0; j < 4; j++) {
            int col = wn * 64 + j * 16 + lq;
            float bias = in_b[512 + bn * 128 + col];
            int cc = col >> 3, cl = col & 7;
#pragma unroll
            for (int i = 0; i < 4; i++) {
                int rbase = wm * 64 + i * 16 + quad * 4;
#pragma unroll
                for (int t = 0; t < 4; t++) {
                    int row = rbase + t;
                    tile[row * 128 + ((cc ^ (row & 15)) << 3) + cl] = (bf16)(acc[i][j][t] + bias);
                }
            }
        }
        __syncthreads();
        for (int idx = tid; idx < 2048; idx += 256) {
            int row = idx >> 4, ch2 = idx & 15;
            bf16x8 v = *(const bf16x8*)(tile + row * 128 + ((ch2 ^ (row & 15)) << 3));
            *(bf16x8*)(kvK + (size_t)(bm * 128 + row) * 512 + bn * 128 + ch2 * 8) = v;
        }
    } else {
        // V half: tileT[col][row], row-chunk swizzled by col
#pragma unroll
        for (int j = 0; j < 4; j++) {
            int col = wn * 64 + j * 16 + lq;
            float bias = in_b[512 + bn * 128 + col];
            int cs = col & 15;
#pragma unroll
            for (int i = 0; i < 4; i++) {
                int rbase = wm * 64 + i * 16 + quad * 4;
#pragma unroll
                for (int t = 0; t < 4; t++) {
                    int row = rbase + t;
                    tile[col * 128 + (((row >> 3) ^ cs) << 3) + (row & 7)] = (bf16)(acc[i][j][t] + bias);
                }
            }
        }
        __syncthreads();
        int b = bm >> 6;
        int m0 = (bm & 63) * 128;
        int hd0 = (bn - 4) * 128;
        for (int idx = tid; idx < 2048; idx += 256) {
            int col = idx >> 4, ch2 = idx & 15;
            bf16x8 v = *(const bf16x8*)(tile + col * 128 + ((ch2 ^ (col & 15)) << 3));
            *(bf16x8*)(Vt + ((size_t)(b * 512 + hd0 + col)) * MM + m0 + ch2 * 8) = v;
        }
    }
}

// ---------------- K8: scores (fp16) + per-chunk softmax stats ----------------
__global__ __launch_bounds__(256) void k_scores(const float* __restrict__ qh,
                                                const bf16* __restrict__ kvK,
                                                const int* __restrict__ mask,
                                                f16* __restrict__ s16,
                                                float* __restrict__ statsM,
                                                float* __restrict__ statsS) {
    __shared__ __align__(16) f16 tile[QQ * 528];
    __shared__ float smx[QQ][4];
    __shared__ float sse[QQ][4];
    __shared__ float qmax[QQ];
    int blk = blockIdx.x;  // 1024 = B*H*16
    int mt = blk & 15, h = (blk >> 4) & 7, b = blk >> 7;
    int tid = threadIdx.x, w = tid >> 6, l = tid & 63;
    int lq = l & 15, quad = l >> 4;
    int mbase = mt * 512 + w * 128;

    bf16x8 af[2][2];
#pragma unroll
    for (int i = 0; i < 2; i++)
#pragma unroll
        for (int s = 0; s < 2; s++) {
            const float* qp = qh + ((size_t)(b * QQ + i * 16 + lq)) * DD + h * 64 + s * 32 + quad * 8;
            f32x4 q0 = *(const f32x4*)qp;
            f32x4 q1 = *(const f32x4*)(qp + 4);
            bf16x8 v;
            v[0] = (bf16)q0.x; v[1] = (bf16)q0.y; v[2] = (bf16)q0.z; v[3] = (bf16)q0.w;
            v[4] = (bf16)q1.x; v[5] = (bf16)q1.y; v[6] = (bf16)q1.z; v[7] = (bf16)q1.w;
            af[i][s] = v;
        }

    const f32x4 vzero = {0.f, 0.f, 0.f, 0.f};
    f32x4 acc[2][8];
#pragma unroll
    for (int i = 0; i < 2; i++)
#pragma unroll
        for (int n = 0; n < 8; n++) acc[i][n] = vzero;

#pragma unroll
    for (int n = 0; n < 8; n++) {
        int m = mbase + n * 16 + lq;
        const bf16* kp = kvK + ((size_t)(b * MM + m)) * 512 + h * 64 + quad * 8;
        bf16x8 b0 = *(const bf16x8*)kp;
        bf16x8 b1 = *(const bf16x8*)(kp + 32);
#pragma unroll
        for (int i = 0; i < 2; i++) {
            acc[i][n] = __builtin_amdgcn_mfma_f32_16x16x32_bf16(af[i][0], b0, acc[i][n], 0, 0, 0);
            acc[i][n] = __builtin_amdgcn_mfma_f32_16x16x32_bf16(af[i][1], b1, acc[i][n], 0, 0, 0);
        }
    }
#pragma unroll
    for (int n = 0; n < 8; n++) {
        int mv = mask[b * MM + mbase + n * 16 + lq];
        if (!mv) {
#pragma unroll
            for (int i = 0; i < 2; i++)
#pragma unroll
                for (int t = 0; t < 4; t++) acc[i][n][t] = NEG_INF;
        }
    }
    float mx[2][4];
#pragma unroll
    for (int i = 0; i < 2; i++)
#pragma unroll
        for (int t = 0; t < 4; t++) {
            float m = acc[i][0][t];
#pragma unroll
            for (int n = 1; n < 8; n++) m = fmaxf(m, acc[i][n][t]);
            mx[i][t] = m;
        }
#pragma unroll
    for (int off = 1; off < 16; off <<= 1)
#pragma unroll
        for (int i = 0; i < 2; i++)
#pragma unroll
            for (int t = 0; t < 4; t++) mx[i][t] = fmaxf(mx[i][t], __shfl_xor(mx[i][t], off, 64));
    if (lq == 0) {
#pragma unroll
        for (int i = 0; i < 2; i++)
#pragma unroll
            for (int t = 0; t < 4; t++) smx[i * 16 + quad * 4 + t][w] = mx[i][t];
    }
    __syncthreads();
    if (tid < QQ) qmax[tid] = fmaxf(fmaxf(smx[tid][0], smx[tid][1]), fmaxf(smx[tid][2], smx[tid][3]));
    __syncthreads();
    float se[2][4];
#pragma unroll
    for (int i = 0; i < 2; i++)
#pragma unroll
        for (int t = 0; t < 4; t++) {
            float qm = qmax[i * 16 + quad * 4 + t];
            float s = 0.f;
#pragma unroll
            for (int n = 0; n < 8; n++) s += __expf(acc[i][n][t] - qm);
            se[i][t] = s;
        }
#pragma unroll
    for (int off = 1; off < 16; off <<= 1)
#pragma unroll
        for (int i = 0; i < 2; i++)
#pragma unroll
            for (int t = 0; t < 4; t++) se[i][t] += __shfl_xor(se[i][t], off, 64);
    if (lq == 0) {
#pragma unroll
        for (int i = 0; i < 2; i++)
#pragma unroll
            for (int t = 0; t < 4; t++) sse[i * 16 + quad * 4 + t][w] = se[i][t];
    }
#pragma unroll
    for (int n = 0; n < 8; n++) {
        int mloc = w * 128 + n * 16 + lq;
#pragma unroll
        for (int i = 0; i < 2; i++)
#pragma unroll
            for (int t = 0; t < 4; t++)
                tile[(i * 16 + quad * 4 + t) * 528 + mloc] = (f16)acc[i][n][t];
    }
    __syncthreads();
    if (tid < QQ) {
        statsM[(size_t)blk * QQ + tid] = qmax[tid];
        statsS[(size_t)blk * QQ + tid] = sse[tid][0] + sse[tid][1] + sse[tid][2] + sse[tid][3];
    }
    for (int it = tid; it < 2048; it += 256) {
        int q = it >> 6, c = it & 63;
        f16x8 v = *(const f16x8*)(tile + q * 528 + c * 8);
        *(f16x8*)(s16 + ((size_t)((b * HH + h) * QQ + q)) * MM + mt * 512 + c * 8) = v;
    }
}

// ---------------- K9: attention head-mean (output 1) ----------------
__global__ __launch_bounds__(256) void k_attn(const f16* __restrict__ s16,
                                              const float* __restrict__ statsM,
                                              const float* __restrict__ statsS,
                                              float* __restrict__ attn_out) {
    __shared__ float cM[128], cS[128], Mh[HH], iLh[HH];
    int blk = blockIdx.x;  // 1024 = B*Q*4
    int ms = blk & 3, q = (blk >> 2) & 31, b = blk >> 7;
    int t = threadIdx.x;
    if (t < 128) {
        int h = t >> 4, c = t & 15;
        size_t sidx = (size_t)(((b * HH + h) * 16 + c)) * QQ + q;
        cM[t] = statsM[sidx];
        cS[t] = statsS[sidx];
    }
    __syncthreads();
    if (t < HH) {
        float M = NEG_INF;
#pragma unroll
        for (int c = 0; c < 16; c++) M = fmaxf(M, cM[t * 16 + c]);
        float L = 0.f;
#pragma unroll
        for (int c = 0; c < 16; c++) L += cS[t * 16 + c] * __expf(cM[t * 16 + c] - M);
        Mh[t] = M;
        iLh[t] = (1.0f / L) * (1.0f / HH);
    }
    __syncthreads();
    int m0 = ms * 2048 + t * 8;
    float am[8];
#pragma unroll
    for (int e = 0; e < 8; e++) am[e] = 0.f;
#pragma unroll
    for (int h = 0; h < HH; h++) {
        f16x8 v = *(const f16x8*)(s16 + ((size_t)((b * HH + h) * QQ + q)) * MM + m0);
        float M = Mh[h], iL = iLh[h];
#pragma unroll
        for (int e = 0; e < 8; e++) am[e] += __expf((float)v[e] - M) * iL;
    }
    float* ao = attn_out + (size_t)(b * QQ + q) * MM + m0;
    f32x4 o0 = {am[0], am[1], am[2], am[3]};
    f32x4 o1 = {am[4], am[5], am[6], am[7]};
    *(f32x4*)ao = o0;
    *(f32x4*)(ao + 4) = o1;
}

// ---------------- K10: ctx = P @ V via MFMA, P computed on the fly ----------------
__global__ __launch_bounds__(256) void k_pv(const f16* __restrict__ s16,
                                            const float* __restrict__ statsM,
                                            const float* __restrict__ statsS,
                                            const bf16* __restrict__ Vt,
                                            float* __restrict__ ctxo_p) {
    __shared__ float ctile[QQ * HDD];
    __shared__ float Mq[QQ], iLq[QQ];
    int blk = blockIdx.x;  // 512 = B*H*8
    int ck = blk & 7, h = (blk >> 3) & 7, b = blk >> 6;
    int t = threadIdx.x, w = t >> 6, l = t & 63;
    int lq = l & 15, quad = l >> 4;
    if (t < QQ) {
        const float* pM = statsM + (size_t)((b * HH + h) * 16) * QQ + t;
        const float* pS = statsS + (size_t)((b * HH + h) * 16) * QQ + t;
        float M = NEG_INF;
#pragma unroll
        for (int c = 0; c < 16; c++) M = fmaxf(M, pM[c * QQ]);
        float L = 0.f;
#pragma unroll
        for (int c = 0; c < 16; c++) L += pS[c * QQ] * __expf(pM[c * QQ] - M);
        Mq[t] = M;
        iLq[t] = 1.0f / L;
    }
    __syncthreads();
    int m0 = ck * 1024 + w * 256;

    const f16* P0 = s16 + ((size_t)((b * HH + h) * QQ + lq)) * MM + m0 + quad * 8;
    const f16* P1 = P0 + (size_t)16 * MM;
    const bf16* Vrow = Vt + ((size_t)((b * HH + h) * HDD + lq)) * MM + m0 + quad * 8;
    float M0 = Mq[lq], iL0 = iLq[lq];
    float M1 = Mq[16 + lq], iL1 = iLq[16 + lq];

    const f32x4 vzero = {0.f, 0.f, 0.f, 0.f};
    f32x4 acc[2][4];
#pragma unroll
    for (int i = 0; i < 2; i++)
#pragma unroll
        for (int j = 0; j < 4; j++) acc[i][j] = vzero;

#pragma unroll 2
    for (int ks = 0; ks < 256; ks += 32) {
        f16x8 r0 = *(const f16x8*)(P0 + ks);
        f16x8 r1 = *(const f16x8*)(P1 + ks);
        bf16x8 a0, a1;
#pragma unroll
        for (int e = 0; e < 8; e++) a0[e] = (bf16)(__expf((float)r0[e] - M0) * iL0);
#pragma unroll
        for (int e = 0; e < 8; e++) a1[e] = (bf16)(__expf((float)r1[e] - M1) * iL1);
        bf16x8 bv[4];
#pragma unroll
        for (int j = 0; j < 4; j++) bv[j] = *(const bf16x8*)(Vrow + (size_t)j * 16 * MM + ks);
#pragma unroll
        for (int j = 0; j < 4; j++) {
            acc[0][j] = __builtin_amdgcn_mfma_f32_16x16x32_bf16(a0, bv[j], acc[0][j], 0, 0, 0);
            acc[1][j] = __builtin_amdgcn_mfma_f32_16x16x32_bf16(a1, bv[j], acc[1][j], 0, 0, 0);
        }
    }
    for (int i = t; i < QQ * HDD; i += 256) ctile[i] = 0.f;
    __syncthreads();
#pragma unroll
    for (int i = 0; i < 2; i++)
#pragma unroll
        for (int j = 0; j < 4; j++)
#pragma unroll
            for (int tt = 0; tt < 4; tt++) {
                int q = i * 16 + quad * 4 + tt;
                int d = j * 16 + lq;
                atomicAdd(&ctile[q * HDD + d], acc[i][j][tt]);
            }
    __syncthreads();
    float* dst = ctxo_p + (size_t)ck * (BB * QQ * DD);
    for (int i = t; i < QQ * HDD; i += 256) {
        int q = i >> 6, d = i & 63;
        dst[((size_t)(b * QQ + q)) * DD + h * HDD + d] = ctile[i];
    }
}

// ---------------- K11: readouts = (sum_c ctxo_p) @ out_w^T + b, gate, LN (out 0) ---
__global__ __launch_bounds__(256) void k_outln(const float* __restrict__ ctxo_p,
                                               const float* __restrict__ out_w,
                                               const float* __restrict__ out_b,
                                               const float* __restrict__ gates,
                                               const float* __restrict__ ln_g,
                                               const float* __restrict__ ln_b,
                                               float* __restrict__ out0) {
    __shared__ float cr[DD];
    __shared__ float sred[4], sred2[4];
    int bq = blockIdx.x, t = threadIdx.x;
    float c0 = 0.f, c1 = 0.f;
#pragma unroll
    for (int c = 0; c < 8; c++) {
        const float* src = ctxo_p + (size_t)c * (BB * QQ * DD) + (size_t)bq * DD;
        c0 += src[t];
        c1 += src[t + 256];
    }
    cr[t] = c0;
    cr[t + 256] = c1;
    __syncthreads();
    float g = gates[bq];
    const f32x4* cv = (const f32x4*)cr;
    float r[2];
#pragma unroll
    for (int jj = 0; jj < 2; jj++) {
        int j = t + jj * 256;
        const f32x4* wv = (const f32x4*)(out_w + (size_t)j * DD);
        float acc = 0.f;
#pragma unroll 4
        for (int k = 0; k < DD / 4; k++) {
            f32x4 wq = wv[k], cq = cv[k];
            acc += wq.x * cq.x + wq.y * cq.y + wq.z * cq.z + wq.w * cq.w;
        }
        r[jj] = (acc + out_b[j]) * g;
    }
    float s1 = r[0] + r[1];
    float s2 = r[0] * r[0] + r[1] * r[1];
    for (int off = 32; off; off >>= 1) {
        s1 += __shfl_xor(s1, off, 64);
        s2 += __shfl_xor(s2, off, 64);
    }
    int wid = t >> 6;
    if ((t & 63) == 0) { sred[wid] = s1; sred2[wid] = s2; }
    __syncthreads();
    float S1 = sred[0] + sred[1] + sred[2] + sred[3];
    float S2 = sred2[0] + sred2[1] + sred2[2] + sred2[3];
    float mu = S1 * (1.0f / DD);
    float var = S2 * (1.0f / DD) - mu * mu;
    float rs = rsqrtf(var + LN_EPS);
#pragma unroll
    for (int jj = 0; jj < 2; jj++) {
        int j = t + jj * 256;
        out0[(size_t)bq * DD + j] = (r[jj] - mu) * rs * ln_g[j] + ln_b[j];
    }
}

extern "C" void kernel_launch(void* const* d_in, const int* in_sizes, int n_in,
                              void* d_out, int out_size, void* d_ws, size_t ws_size,
                              hipStream_t stream) {
    const float* memory  = (const float*)d_in[0];
    const float* context = (const float*)d_in[1];
    const int*   mask    = (const int*)d_in[2];
    const float* qp      = (const float*)d_in[3];
    const float* ctx_w   = (const float*)d_in[4];
    const float* ctx_b   = (const float*)d_in[5];
    const float* in_w    = (const float*)d_in[6];
    const float* in_b    = (const float*)d_in[7];
    const float* out_w   = (const float*)d_in[8];
    const float* out_b   = (const float*)d_in[9];
    const float* ln_g    = (const float*)d_in[10];
    const float* ln_b    = (const float*)d_in[11];
    const float* gate_w  = (const float*)d_in[12];
    const float* gate_b  = (const float*)d_in[13];

    float* out       = (float*)d_out;
    float* out_ln    = out;                       // (B,Q,D)   131072
    float* out_attn  = out + 131072;              // (B,Q,M)   2097152
    float* out_gates = out + 131072 + 2097152;    // (B,Q)     256
    float* out_q     = out_gates + 256;           // (B,Q,D)   131072

    char* ws = (char*)d_ws;
    bf16*  memB   = (bf16*)ws;                        // [0, 64MB); dead after gemm
    f16*   s16    = (f16*)ws;                         // alias: 33.5 MB fp16 scores
    bf16*  kvK    = (bf16*)(ws + 67108864);           // 64 MB
    bf16*  Vt     = (bf16*)(ws + 134217728);          // 64 MB
    bf16*  kvwB   = (bf16*)(ws + 201326592);          // 256 KB
    float* statsM = (float*)(ws + 201588736);         // 128 KB
    float* statsS = (float*)(ws + 201719808);         // 128 KB
    float* qh     = (float*)(ws + 202375168);         // 512 KB
    float* ctxo_p = (float*)(ws + 202899456);         // 4 MB (8 chunks)

    k_front<<<64, 512, 0, stream>>>(context, ctx_w, ctx_b, qp, gate_w, gate_b, out_q, out_gates);
    k_qh<<<64, 256, 0, stream>>>(out_q, in_w, in_b, qh);
    k_cvt<<<32768, 256, 0, stream>>>(memory, memB, 8388608);
    k_cvt<<<512, 256, 0, stream>>>(in_w + 262144, kvwB, 131072);
    k_gemm_kv<<<4096, 256, 0, stream>>>(memB, kvwB, in_b, kvK, Vt);
    k_scores<<<1024, 256, 0, stream>>>(qh, kvK, mask, s16, statsM, statsS);
    k_attn<<<1024, 256, 0, stream>>>(s16, statsM, statsS, out_attn);
    k_pv<<<512, 256, 0, stream>>>(s16, statsM, statsS, Vt, ctxo_p);
    k_outln<<<BB * QQ, 256, 0, stream>>>(ctxo_p, out_w, out_b, out_gates, ln_g, ln_b, out_ln);
}